// Round 4
// baseline (6630.993 us; speedup 1.0000x reference)
//
#include <hip/hip_runtime.h>
#include <hip/hip_bf16.h>
#include <hip/hip_cooperative_groups.h>

namespace cg = cooperative_groups;

typedef unsigned short u16;
typedef unsigned int u32;
typedef __attribute__((ext_vector_type(4))) float f32x4;
typedef __attribute__((ext_vector_type(8))) short s16x8;

#define OREC 8388608
#define OH 16777216
#define OLOSS 17301504

__device__ __forceinline__ float bf2f(u16 u) {
    union { u32 i; float f; } v; v.i = ((u32)u) << 16; return v.f;
}
__device__ __forceinline__ u16 f2bf(float f) {
    union { float f; u32 i; } v; v.f = f;
    u32 i = v.i;
    u32 r = i + 0x7FFFu + ((i >> 16) & 1u);
    return (u16)(r >> 16);
}
__device__ __forceinline__ float ldin(const void* p, int i, int bf) {
    return bf ? bf2f(((const u16*)p)[i]) : ((const float*)p)[i];
}
__device__ __forceinline__ void stout(void* p, int i, float v, int bf) {
    if (bf) ((u16*)p)[i] = f2bf(v); else ((float*)p)[i] = v;
}

#define ZACC(A) do { \
    _Pragma("unroll") for (int zi = 0; zi < 2; ++zi) \
    _Pragma("unroll") for (int zj = 0; zj < 2; ++zj) \
    _Pragma("unroll") for (int zq = 0; zq < 4; ++zq) A[zi][zj][zq] = 0.f; \
} while (0)

// ---- legacy 64x64 GEMM core (one-time gammaH/beta precompute) ----
__device__ __forceinline__ void stage_tile(const u16* __restrict__ src, int ld, int row0, int k0,
                                           u16* lds) {
    int t = threadIdx.x;
    int row = t >> 2, seg = t & 3;
    const u16* g = src + (size_t)(row0 + row) * ld + k0 + (seg << 3);
    uint4 v = *(const uint4*)g;
    *(uint4*)&lds[(row << 5) + ((seg ^ (row & 3)) << 3)] = v;
}

__device__ __forceinline__ void gemm_loop(const u16* __restrict__ A, int lda,
                                          const u16* __restrict__ W, int ldw,
                                          int K, int m0, int n0,
                                          u16* lA, u16* lB, f32x4 acc[2][2]) {
    int lane = threadIdx.x & 63;
    int wid = threadIdx.x >> 6;
    int wr = wid >> 1, wc = wid & 1;
    int lrow = lane & 15, lseg = lane >> 4;
    int sw = (lseg ^ (lrow & 3)) << 3;
    for (int k0 = 0; k0 < K; k0 += 32) {
        __syncthreads();
        stage_tile(A, lda, m0, k0, lA);
        stage_tile(W, ldw, n0, k0, lB);
        __syncthreads();
        s16x8 af[2], bg[2];
#pragma unroll
        for (int i = 0; i < 2; i++) {
            int r = (wr << 5) + (i << 4) + lrow;
            af[i] = *(const s16x8*)&lA[(r << 5) + sw];
            int c = (wc << 5) + (i << 4) + lrow;
            bg[i] = *(const s16x8*)&lB[(c << 5) + sw];
        }
#pragma unroll
        for (int i = 0; i < 2; i++)
#pragma unroll
            for (int j = 0; j < 2; j++)
                acc[i][j] = __builtin_amdgcn_mfma_f32_16x16x32_bf16(af[i], bg[j], acc[i][j], 0, 0, 0);
    }
}

// ---- prologue kernels ----
__global__ void k_zero(int* flag, float* lossN, float* lossD) {
    if (threadIdx.x == 0) *flag = 0;
    if (threadIdx.x < 64) { lossN[threadIdx.x] = 0.f; lossD[threadIdx.x] = 0.f; }
}

__global__ void k_detect(const u32* __restrict__ w, int* flag) {
    int gid = blockIdx.x * 256 + threadIdx.x;
    int found = 0;
    for (int i = gid; i < (1 << 20); i += 65536) {
        if ((w[i] & 0xFFFFu) == 0x3F80u) found = 1;
    }
    if (found) atomicOr(flag, 1);
}

__global__ void k_cvt_bf(const void* __restrict__ src, u16* __restrict__ dst, int n,
                         const int* __restrict__ flagp) {
    int bf = *flagp;
    for (int i = blockIdx.x * 256 + threadIdx.x; i < n; i += gridDim.x * 256)
        dst[i] = bf ? ((const u16*)src)[i] : f2bf(((const float*)src)[i]);
}

// merged bias conversion: [0,1024)=bdh [1024,1280)=bdx [1280,1536)=bh
// [1536,1792)=bfr [1792,2048)=bwc [2048,5120)=bih [5120,8192)=bhh
__global__ void k_cvt_biases(const void* __restrict__ bdh, const void* __restrict__ bdx,
                             const void* __restrict__ bh, const void* __restrict__ bfr,
                             const void* __restrict__ bwc, const void* __restrict__ bih,
                             const void* __restrict__ bhh, float* __restrict__ dst,
                             const int* __restrict__ flagp) {
    int bf = *flagp;
    int i = blockIdx.x * 256 + threadIdx.x;  // 8192
    const void* src; int off;
    if (i < 1024) { src = bdh; off = 0; }
    else if (i < 1280) { src = bdx; off = 1024; }
    else if (i < 1536) { src = bh; off = 1280; }
    else if (i < 1792) { src = bfr; off = 1536; }
    else if (i < 2048) { src = bwc; off = 1792; }
    else if (i < 5120) { src = bih; off = 2048; }
    else { src = bhh; off = 5120; }
    dst[i] = ldin(src, i - off, bf);
}

__global__ void k_fixup(u16* __restrict__ WfrB, float* __restrict__ wdxd,
                        const void* __restrict__ Wdx, const int* __restrict__ flagp) {
    int f = threadIdx.x;  // 256
    int bf = *flagp;
    WfrB[f * 256 + f] = 0;
    wdxd[f] = ldin(Wdx, f * 257, bf);
}

// ---- precompute kernels ----
__global__ void k_pack(const void* __restrict__ deltas, const void* __restrict__ mask,
                       const int* __restrict__ flagp,
                       const float* __restrict__ wdxd, const float* __restrict__ bdx,
                       u16* __restrict__ dbf_all, u16* __restrict__ A2_all) {
    int bf = *flagp;
    for (int idx = blockIdx.x * 256 + threadIdx.x; idx < 8388608; idx += gridDim.x * 256) {
        int f = idx & 255;
        int bt = idx >> 8;
        int b = bt >> 6, t = bt & 63;
        float d = ldin(deltas, idx, bf);
        float m = ldin(mask, idx, bf);
        int r = t * 512 + b;
        dbf_all[(r << 8) + f] = f2bf(d);
        float gx = expf(-fmaxf(d * wdxd[f] + bdx[f], 0.f));
        A2_all[(r << 9) + f] = f2bf(gx);
        A2_all[(r << 9) + 256 + f] = f2bf(m);
    }
}

__global__ __launch_bounds__(256) void k_gammaH(const u16* __restrict__ dbf_all,
                                                const u16* __restrict__ WdhB,
                                                const float* __restrict__ bdh,
                                                u16* __restrict__ gammaH) {
    __shared__ u16 lA[2048], lB[2048];
    int m0 = blockIdx.x << 6, n0 = blockIdx.y << 6;
    f32x4 acc[2][2]; ZACC(acc);
    gemm_loop(dbf_all, 256, WdhB, 256, 256, m0, n0, lA, lB, acc);
    int lane = threadIdx.x & 63, wid = threadIdx.x >> 6;
    int wr = wid >> 1, wc = wid & 1;
    int rq = (lane >> 4) << 2, cc = lane & 15;
#pragma unroll
    for (int i = 0; i < 2; i++)
#pragma unroll
        for (int j = 0; j < 2; j++)
#pragma unroll
            for (int q = 0; q < 4; q++) {
                int gr = m0 + (wr << 5) + (i << 4) + rq + q;
                int gc = n0 + (wc << 5) + (j << 4) + cc;
                gammaH[((size_t)gr << 10) + gc] = f2bf(expf(-fmaxf(acc[i][j][q] + bdh[gc], 0.f)));
            }
}

__global__ __launch_bounds__(256) void k_beta(const u16* __restrict__ A2_all,
                                              const u16* __restrict__ WwcB,
                                              const float* __restrict__ bwc,
                                              float* __restrict__ beta_all) {
    __shared__ u16 lA[2048], lB[2048];
    int m0 = blockIdx.x << 6, n0 = blockIdx.y << 6;
    f32x4 acc[2][2]; ZACC(acc);
    gemm_loop(A2_all, 512, WwcB, 512, 512, m0, n0, lA, lB, acc);
    int lane = threadIdx.x & 63, wid = threadIdx.x >> 6;
    int wr = wid >> 1, wc = wid & 1;
    int rq = (lane >> 4) << 2, cc = lane & 15;
#pragma unroll
    for (int i = 0; i < 2; i++)
#pragma unroll
        for (int j = 0; j < 2; j++)
#pragma unroll
            for (int q = 0; q < 4; q++) {
                int gr = m0 + (wr << 5) + (i << 4) + rq + q;
                int gc = n0 + (wc << 5) + (j << 4) + cc;
                beta_all[((size_t)gr << 8) + gc] = acc[i][j][q] + bwc[gc];
            }
}

__global__ void k_hinit(const void* __restrict__ h0, const int* __restrict__ flagp,
                        const u16* __restrict__ gammaH,
                        float* __restrict__ h, u16* __restrict__ hbf) {
    int bf = *flagp;
    int i = blockIdx.x * 256 + threadIdx.x;  // 524288
    float g = bf2f(gammaH[i]);
    float hv = ldin(h0, i, bf) * g;
    h[i] = hv;
    hbf[i] = f2bf(hv);
}

// ---- persistent cooperative kernel ----
struct KParams {
    const u16 *WhB, *WfrB, *WihB, *WhhB;
    const float *biases, *beta_all;
    const u16 *gammaH;
    u16 *hbfA, *hbfB, *A3;
    float *h;
    const void *x, *mask;
    const int* flagp;
    void* out;
    float *lossN, *lossD;
};

// gates accumulation part: tile 32 rows x (64 hcols x 3 gates), K in chunks of 64,
// double-buffered LDS (1 barrier/chunk), reg prefetch. b0/b1 are 16128-u16 buffers:
// B region [0,13824) = 192 rows x 72 (pad), A region [13824,16128) = 32 rows x 72.
__device__ __forceinline__ void gates_part(
    const u16* __restrict__ Ap, int ldA,
    const u16* __restrict__ Bp, int ldB, int nch,
    int m0g, int n0, int tid, u16* b0, u16* b1,
    f32x4& aR, f32x4& aZ, f32x4& aN) {
    const int lane = tid & 63, w = tid >> 6;
    const int wr = w >> 2, wc = w & 3;
    const int lrow = lane & 15, lseg = lane >> 4;
    const int arow = tid >> 3, aoff = (tid & 7) << 3;
    const u16* Ag = Ap + (size_t)(m0g + (arow & 31)) * ldA + aoff;
    const u16* Bg0 = Bp + (size_t)(n0 + arow) * ldB + aoff;
    const u16* Bg1 = Bg0 + (size_t)1024 * ldB;
    const u16* Bg2 = Bg1 + (size_t)1024 * ldB;
    uint4 pa, pb0, pb1, pb2;
    auto ld = [&](int k0) {
        if (tid < 256) pa = *(const uint4*)(Ag + k0);
        pb0 = *(const uint4*)(Bg0 + k0);
        pb1 = *(const uint4*)(Bg1 + k0);
        pb2 = *(const uint4*)(Bg2 + k0);
    };
    auto st = [&](u16* lb) {
        *(uint4*)&lb[arow * 72 + aoff] = pb0;
        *(uint4*)&lb[(64 + arow) * 72 + aoff] = pb1;
        *(uint4*)&lb[(128 + arow) * 72 + aoff] = pb2;
        if (tid < 256) *(uint4*)&lb[13824 + arow * 72 + aoff] = pa;
    };
    ld(0);
    st(b0);
    __syncthreads();
    int cur = 0;
#pragma unroll 1
    for (int it = 0; it < nch; ++it) {
        if (it + 1 < nch) ld((it + 1) << 6);
        u16* lc = cur ? b1 : b0;
#pragma unroll
        for (int s = 0; s < 2; ++s) {
            int kk = (s << 5) + (lseg << 3);
            s16x8 a = *(const s16x8*)&lc[13824 + (wr * 16 + lrow) * 72 + kk];
            s16x8 br = *(const s16x8*)&lc[((wc << 4) + lrow) * 72 + kk];
            aR = __builtin_amdgcn_mfma_f32_16x16x32_bf16(a, br, aR, 0, 0, 0);
            s16x8 bz = *(const s16x8*)&lc[(64 + (wc << 4) + lrow) * 72 + kk];
            aZ = __builtin_amdgcn_mfma_f32_16x16x32_bf16(a, bz, aZ, 0, 0, 0);
            s16x8 bn = *(const s16x8*)&lc[(128 + (wc << 4) + lrow) * 72 + kk];
            aN = __builtin_amdgcn_mfma_f32_16x16x32_bf16(a, bn, aN, 0, 0, 0);
        }
        if (it + 1 < nch) st(cur ? b0 : b1);
        __syncthreads();
        cur ^= 1;
    }
}

__global__ __launch_bounds__(512) void k_main(KParams P) {
    __shared__ u16 smem[32256];
    __shared__ float redN[8], redD[8];
    u16* b0 = smem;
    u16* b1 = smem + 16128;
    u16* lH = smem;                 // 16 x 1032  (phase A, overlaps b0/b1)
    u16* lXR = smem + 16512;        // 16 x 264

    cg::grid_group grid = cg::this_grid();
    const int tid = threadIdx.x;
    const int bid = blockIdx.x;
    const int lane = tid & 63, w = tid >> 6;
    const int lrow = lane & 15, lseg = lane >> 4;
    const int bf = *P.flagp;

    // gates tile for this block: rows mt*32, hcols nt*64
    const int mt = bid >> 4, nt = bid & 15;
    const int m0g = mt << 5, n0 = nt << 6;
    const int wr = w >> 2, wc = w & 3;

    for (int t = 0; t < 64; ++t) {
        const u16* hcur = (t & 1) ? P.hbfB : P.hbfA;
        u16* hnxt = (t & 1) ? P.hbfA : P.hbfB;

        // ---- phase A (blocks 0..31): hist + feature-reg + combine -> A3, loss ----
        if (bid < 32) {
            const int m0 = bid << 4;
            {
                int row = tid >> 5;
                const u16* src = hcur + ((size_t)(m0 + row) << 10);
#pragma unroll
                for (int j = 0; j < 4; ++j) {
                    int off = ((tid & 31) + (j << 5)) << 3;
                    *(uint4*)&lH[row * 1032 + off] = *(const uint4*)&src[off];
                }
            }
            __syncthreads();
            const int c0 = w << 5;
            f32x4 acc[2] = {};
#pragma unroll 4
            for (int k0 = 0; k0 < 1024; k0 += 32) {
                int kk = k0 + (lseg << 3);
                s16x8 a = *(const s16x8*)&lH[lrow * 1032 + kk];
#pragma unroll
                for (int j = 0; j < 2; ++j) {
                    s16x8 b = *(const s16x8*)&P.WhB[((size_t)(c0 + (j << 4) + lrow) << 10) + kk];
                    acc[j] = __builtin_amdgcn_mfma_f32_16x16x32_bf16(a, b, acc[j], 0, 0, 0);
                }
            }
            float xhr[2][4], mvr[2][4], xvr[2][4];
#pragma unroll
            for (int j = 0; j < 2; ++j) {
                int gc = c0 + (j << 4) + lrow;
                float bhc = P.biases[1280 + gc];
#pragma unroll
                for (int q = 0; q < 4; ++q) {
                    int r = (lseg << 2) + q;
                    float v = acc[j][q] + bhc;
                    int gidx = ((m0 + r) << 14) + (t << 8) + gc;
                    float mv = ldin(P.mask, gidx, bf);
                    float xv = ldin(P.x, gidx, bf);
                    xhr[j][q] = v; mvr[j][q] = mv; xvr[j][q] = xv;
                    lXR[r * 264 + gc] = f2bf(mv * xv + (1.f - mv) * v);
                }
            }
            __syncthreads();
            f32x4 accF[2] = {};
#pragma unroll 2
            for (int k0 = 0; k0 < 256; k0 += 32) {
                int kk = k0 + (lseg << 3);
                s16x8 a = *(const s16x8*)&lXR[lrow * 264 + kk];
#pragma unroll
                for (int j = 0; j < 2; ++j) {
                    s16x8 b = *(const s16x8*)&P.WfrB[((size_t)(c0 + (j << 4) + lrow) << 8) + kk];
                    accF[j] = __builtin_amdgcn_mfma_f32_16x16x32_bf16(a, b, accF[j], 0, 0, 0);
                }
            }
            float ln = 0.f, ldn = 0.f;
#pragma unroll
            for (int j = 0; j < 2; ++j) {
                int gc = c0 + (j << 4) + lrow;
                float bfrc = P.biases[1536 + gc];
#pragma unroll
                for (int q = 0; q < 4; ++q) {
                    int r = (lseg << 2) + q;
                    int gr = m0 + r;
                    float xu = accF[j][q] + bfrc;
                    float beta = P.beta_all[(((size_t)t * 512 + gr) << 8) + gc];
                    float xc = beta * xu + (1.f - beta) * xhr[j][q];
                    int gidx = (gr << 14) + (t << 8) + gc;
                    float mv = mvr[j][q], xv = xvr[j][q];
                    stout(P.out, OREC + gidx, xc, bf);
                    float xi = mv * xv + (1.f - mv) * xc;
                    stout(P.out, gidx, xi, bf);
                    P.A3[(gr << 9) + gc] = f2bf(xi);
                    P.A3[(gr << 9) + 256 + gc] = f2bf(mv);
                    ln += fabsf(xc - xv) * mv;
                    ldn += mv;
                }
            }
            for (int o = 32; o > 0; o >>= 1) { ln += __shfl_down(ln, o); ldn += __shfl_down(ldn, o); }
            if (lane == 0) { redN[w] = ln; redD[w] = ldn; }
            __syncthreads();
            if (tid == 0) {
                float sn = 0.f, sd = 0.f;
#pragma unroll
                for (int i = 0; i < 8; ++i) { sn += redN[i]; sd += redD[i]; }
                atomicAdd(&P.lossN[t], sn);
                atomicAdd(&P.lossD[t], sd);
            }
            __syncthreads();
        }

        // ---- stage 1 (all blocks): gh part, K=1024 (does not need A3) ----
        f32x4 aR = {0.f, 0.f, 0.f, 0.f}, aZ = {0.f, 0.f, 0.f, 0.f};
        f32x4 aNi = {0.f, 0.f, 0.f, 0.f}, aNh = {0.f, 0.f, 0.f, 0.f};
        gates_part(hcur, 1024, P.WhhB, 1024, 16, m0g, n0, tid, b0, b1, aR, aZ, aNh);

        grid.sync();   // A3 ready (phase A done), gh accumulated

        // ---- stage 2 (all blocks): gi part, K=512, then GRU + decay ----
        gates_part(P.A3, 512, P.WihB, 512, 8, m0g, n0, tid, b0, b1, aR, aZ, aNi);

        {
            const int gc = n0 + (wc << 4) + lrow;
            float bR = P.biases[2048 + gc] + P.biases[5120 + gc];
            float bZ = P.biases[3072 + gc] + P.biases[6144 + gc];
            float bNi = P.biases[4096 + gc];
            float bNh = P.biases[7168 + gc];
#pragma unroll
            for (int q = 0; q < 4; ++q) {
                int gr = m0g + (wr << 4) + (lseg << 2) + q;
                float rr = 1.f / (1.f + expf(-(aR[q] + bR)));
                float zz = 1.f / (1.f + expf(-(aZ[q] + bZ)));
                float nn = tanhf(aNi[q] + bNi + rr * (aNh[q] + bNh));
                int idx = (gr << 10) + gc;
                float hv = (1.f - zz) * nn + zz * P.h[idx];
                if (t < 63) {
                    hv *= bf2f(P.gammaH[(((size_t)(t + 1) * 512 + gr) << 10) + gc]);
                    P.h[idx] = hv;
                    hnxt[idx] = f2bf(hv);
                } else {
                    stout(P.out, OH + idx, hv, bf);
                }
            }
        }

        grid.sync();   // h / hbf_next ready for next step
    }

    // ---- final loss ----
    if (bid == 0 && tid < 64) {
        float v = P.lossN[tid] / (P.lossD[tid] + 1e-12f);
        for (int o = 32; o > 0; o >>= 1) v += __shfl_down(v, o);
        if (tid == 0) {
            stout(P.out, OLOSS, v, bf);
            stout(P.out, OLOSS + 1, 0.f, bf);
        }
    }
}

extern "C" void kernel_launch(void* const* d_in, const int* in_sizes, int n_in,
                              void* d_out, int out_size, void* d_ws, size_t ws_size,
                              hipStream_t stream) {
    (void)in_sizes; (void)n_in; (void)out_size; (void)ws_size;
    const void* x = d_in[0];
    const void* mask = d_in[1];
    const void* deltas = d_in[2];
    const void* h0 = d_in[3];
    const void* Wdh = d_in[4];  const void* bdh = d_in[5];
    const void* Wdx = d_in[6];  const void* bdx = d_in[7];
    const void* Wh = d_in[8];   const void* bh = d_in[9];
    const void* Wfr = d_in[10]; const void* bfr = d_in[11];
    const void* Wwc = d_in[12]; const void* bwc = d_in[13];
    const void* Wih = d_in[14]; const void* bih = d_in[15];
    const void* Whh = d_in[16]; const void* bhh = d_in[17];

    char* cur = (char*)d_ws;
    auto carve = [&](size_t bytes) -> char* {
        char* p = cur; cur += (bytes + 255) & ~(size_t)255; return p;
    };
    int* flag = (int*)carve(sizeof(int));
    float* lossN = (float*)carve(64 * 4);
    float* lossD = (float*)carve(64 * 4);
    float* wdxd = (float*)carve(256 * 4);
    float* biasesF = (float*)carve(8192 * 4);
    u16* WdhB = (u16*)carve(262144 * 2);
    u16* WhB = (u16*)carve(262144 * 2);
    u16* WfrB = (u16*)carve(65536 * 2);
    u16* WwcB = (u16*)carve(131072 * 2);
    u16* WihB = (u16*)carve(1572864 * 2);
    u16* WhhB = (u16*)carve(3145728 * 2);
    float* h = (float*)carve(524288 * 4);
    u16* hbf0 = (u16*)carve(524288 * 2);
    u16* hbf1 = (u16*)carve(524288 * 2);
    u16* A3 = (u16*)carve(262144 * 2);
    u16* dbf_all = (u16*)carve((size_t)8388608 * 2);
    u16* A2_all = (u16*)carve((size_t)16777216 * 2);
    u16* gammaH_all = (u16*)carve((size_t)33554432 * 2);
    float* beta_all = (float*)carve((size_t)8388608 * 4);

    float* bdhF = biasesF;
    float* bdxF = biasesF + 1024;

    // prologue: dtype detect + weight prep
    k_zero<<<1, 64, 0, stream>>>(flag, lossN, lossD);
    k_detect<<<256, 256, 0, stream>>>((const u32*)mask, flag);
    k_cvt_bf<<<1024, 256, 0, stream>>>(Wdh, WdhB, 262144, flag);
    k_cvt_bf<<<1024, 256, 0, stream>>>(Wh, WhB, 262144, flag);
    k_cvt_bf<<<256, 256, 0, stream>>>(Wfr, WfrB, 65536, flag);
    k_cvt_bf<<<512, 256, 0, stream>>>(Wwc, WwcB, 131072, flag);
    k_cvt_bf<<<2048, 256, 0, stream>>>(Wih, WihB, 1572864, flag);
    k_cvt_bf<<<2048, 256, 0, stream>>>(Whh, WhhB, 3145728, flag);
    k_cvt_biases<<<32, 256, 0, stream>>>(bdh, bdx, bh, bfr, bwc, bih, bhh, biasesF, flag);
    k_fixup<<<1, 256, 0, stream>>>(WfrB, wdxd, Wdx, flag);

    // precompute: gamma_x/mask pack, gamma_h for all t, beta for all t
    k_pack<<<8192, 256, 0, stream>>>(deltas, mask, flag, wdxd, bdxF, dbf_all, A2_all);
    k_gammaH<<<dim3(512, 16), 256, 0, stream>>>(dbf_all, WdhB, bdhF, gammaH_all);
    k_beta<<<dim3(512, 4), 256, 0, stream>>>(A2_all, WwcB, biasesF + 1792, beta_all);
    k_hinit<<<2048, 256, 0, stream>>>(h0, flag, gammaH_all, h, hbf0);

    // persistent cooperative kernel: whole T-loop
    KParams prm;
    prm.WhB = WhB; prm.WfrB = WfrB; prm.WihB = WihB; prm.WhhB = WhhB;
    prm.biases = biasesF; prm.beta_all = beta_all; prm.gammaH = gammaH_all;
    prm.hbfA = hbf0; prm.hbfB = hbf1; prm.A3 = A3;
    prm.h = h;
    prm.x = x; prm.mask = mask;
    prm.flagp = flag;
    prm.out = d_out;
    prm.lossN = lossN; prm.lossD = lossD;
    void* args[] = { &prm };
    hipLaunchCooperativeKernel((const void*)k_main, dim3(256), dim3(512), args, 0, stream);
}

// Round 5
// 5726.437 us; speedup vs baseline: 1.1580x; 1.1580x over previous
//
#include <hip/hip_runtime.h>
#include <hip/hip_bf16.h>

typedef unsigned short u16;
typedef unsigned int u32;
typedef __attribute__((ext_vector_type(4))) float f32x4;
typedef __attribute__((ext_vector_type(8))) short s16x8;

#define OREC 8388608
#define OH 16777216
#define OLOSS 17301504

__device__ __forceinline__ float bf2f(u16 u) {
    union { u32 i; float f; } v; v.i = ((u32)u) << 16; return v.f;
}
__device__ __forceinline__ u16 f2bf(float f) {
    union { float f; u32 i; } v; v.f = f;
    u32 i = v.i;
    u32 r = i + 0x7FFFu + ((i >> 16) & 1u);
    return (u16)(r >> 16);
}
__device__ __forceinline__ float ldin(const void* p, int i, int bf) {
    return bf ? bf2f(((const u16*)p)[i]) : ((const float*)p)[i];
}
__device__ __forceinline__ void stout(void* p, int i, float v, int bf) {
    if (bf) ((u16*)p)[i] = f2bf(v); else ((float*)p)[i] = v;
}

#define ZACC(A) do { \
    _Pragma("unroll") for (int zi = 0; zi < 2; ++zi) \
    _Pragma("unroll") for (int zj = 0; zj < 2; ++zj) \
    _Pragma("unroll") for (int zq = 0; zq < 4; ++zq) A[zi][zj][zq] = 0.f; \
} while (0)

// ---- legacy 64x64 GEMM core (one-time gammaH/beta precompute) ----
__device__ __forceinline__ void stage_tile(const u16* __restrict__ src, int ld, int row0, int k0,
                                           u16* lds) {
    int t = threadIdx.x;
    int row = t >> 2, seg = t & 3;
    const u16* g = src + (size_t)(row0 + row) * ld + k0 + (seg << 3);
    uint4 v = *(const uint4*)g;
    *(uint4*)&lds[(row << 5) + ((seg ^ (row & 3)) << 3)] = v;
}

__device__ __forceinline__ void gemm_loop(const u16* __restrict__ A, int lda,
                                          const u16* __restrict__ W, int ldw,
                                          int K, int m0, int n0,
                                          u16* lA, u16* lB, f32x4 acc[2][2]) {
    int lane = threadIdx.x & 63;
    int wid = threadIdx.x >> 6;
    int wr = wid >> 1, wc = wid & 1;
    int lrow = lane & 15, lseg = lane >> 4;
    int sw = (lseg ^ (lrow & 3)) << 3;
    for (int k0 = 0; k0 < K; k0 += 32) {
        __syncthreads();
        stage_tile(A, lda, m0, k0, lA);
        stage_tile(W, ldw, n0, k0, lB);
        __syncthreads();
        s16x8 af[2], bg[2];
#pragma unroll
        for (int i = 0; i < 2; i++) {
            int r = (wr << 5) + (i << 4) + lrow;
            af[i] = *(const s16x8*)&lA[(r << 5) + sw];
            int c = (wc << 5) + (i << 4) + lrow;
            bg[i] = *(const s16x8*)&lB[(c << 5) + sw];
        }
#pragma unroll
        for (int i = 0; i < 2; i++)
#pragma unroll
            for (int j = 0; j < 2; j++)
                acc[i][j] = __builtin_amdgcn_mfma_f32_16x16x32_bf16(af[i], bg[j], acc[i][j], 0, 0, 0);
    }
}

// ---- prologue kernels ----
__global__ void k_zero(int* flag, float* lossN, float* lossD) {
    if (threadIdx.x == 0) *flag = 0;
    if (threadIdx.x < 64) { lossN[threadIdx.x] = 0.f; lossD[threadIdx.x] = 0.f; }
}

__global__ void k_detect(const u32* __restrict__ w, int* flag) {
    int gid = blockIdx.x * 256 + threadIdx.x;
    int found = 0;
    for (int i = gid; i < (1 << 20); i += 65536) {
        if ((w[i] & 0xFFFFu) == 0x3F80u) found = 1;
    }
    if (found) atomicOr(flag, 1);
}

__global__ void k_cvt_bf(const void* __restrict__ src, u16* __restrict__ dst, int n,
                         const int* __restrict__ flagp) {
    int bf = *flagp;
    for (int i = blockIdx.x * 256 + threadIdx.x; i < n; i += gridDim.x * 256)
        dst[i] = bf ? ((const u16*)src)[i] : f2bf(((const float*)src)[i]);
}

// W2[c][k] : k<512 -> Wih[c][k]; else Whh[c][k-512].  c in [0,3072), ld 1536
__global__ void k_packW2(const void* __restrict__ Wih, const void* __restrict__ Whh,
                         u16* __restrict__ W2B, const int* __restrict__ flagp) {
    int bf = *flagp;
    int c = blockIdx.x;       // 3072
    int k0 = threadIdx.x;     // 256
#pragma unroll
    for (int j = 0; j < 6; ++j) {
        int k = k0 + (j << 8);
        float v = (k < 512) ? ldin(Wih, c * 512 + k, bf)
                            : ldin(Whh, c * 1024 + (k - 512), bf);
        W2B[(size_t)c * 1536 + k] = f2bf(v);
    }
}

// merged bias conversion: [0,1024)=bdh [1024,1280)=bdx [1280,1536)=bh
// [1536,1792)=bfr [1792,2048)=bwc [2048,5120)=bih [5120,8192)=bhh
__global__ void k_cvt_biases(const void* __restrict__ bdh, const void* __restrict__ bdx,
                             const void* __restrict__ bh, const void* __restrict__ bfr,
                             const void* __restrict__ bwc, const void* __restrict__ bih,
                             const void* __restrict__ bhh, float* __restrict__ dst,
                             const int* __restrict__ flagp) {
    int bf = *flagp;
    int i = blockIdx.x * 256 + threadIdx.x;  // 8192
    const void* src; int off;
    if (i < 1024) { src = bdh; off = 0; }
    else if (i < 1280) { src = bdx; off = 1024; }
    else if (i < 1536) { src = bh; off = 1280; }
    else if (i < 1792) { src = bfr; off = 1536; }
    else if (i < 2048) { src = bwc; off = 1792; }
    else if (i < 5120) { src = bih; off = 2048; }
    else { src = bhh; off = 5120; }
    dst[i] = ldin(src, i - off, bf);
}

__global__ void k_fixup(u16* __restrict__ WfrB, float* __restrict__ wdxd,
                        const void* __restrict__ Wdx, const int* __restrict__ flagp) {
    int f = threadIdx.x;  // 256
    int bf = *flagp;
    WfrB[f * 256 + f] = 0;
    wdxd[f] = ldin(Wdx, f * 257, bf);
}

// ---- precompute kernels ----
__global__ void k_pack(const void* __restrict__ deltas, const void* __restrict__ mask,
                       const int* __restrict__ flagp,
                       const float* __restrict__ wdxd, const float* __restrict__ bdx,
                       u16* __restrict__ dbf_all, u16* __restrict__ A2_all) {
    int bf = *flagp;
    for (int idx = blockIdx.x * 256 + threadIdx.x; idx < 8388608; idx += gridDim.x * 256) {
        int f = idx & 255;
        int bt = idx >> 8;
        int b = bt >> 6, t = bt & 63;
        float d = ldin(deltas, idx, bf);
        float m = ldin(mask, idx, bf);
        int r = t * 512 + b;
        dbf_all[(r << 8) + f] = f2bf(d);
        float gx = expf(-fmaxf(d * wdxd[f] + bdx[f], 0.f));
        A2_all[(r << 9) + f] = f2bf(gx);
        A2_all[(r << 9) + 256 + f] = f2bf(m);
    }
}

__global__ __launch_bounds__(256) void k_gammaH(const u16* __restrict__ dbf_all,
                                                const u16* __restrict__ WdhB,
                                                const float* __restrict__ bdh,
                                                u16* __restrict__ gammaH) {
    __shared__ u16 lA[2048], lB[2048];
    int m0 = blockIdx.x << 6, n0 = blockIdx.y << 6;
    f32x4 acc[2][2]; ZACC(acc);
    gemm_loop(dbf_all, 256, WdhB, 256, 256, m0, n0, lA, lB, acc);
    int lane = threadIdx.x & 63, wid = threadIdx.x >> 6;
    int wr = wid >> 1, wc = wid & 1;
    int rq = (lane >> 4) << 2, cc = lane & 15;
#pragma unroll
    for (int i = 0; i < 2; i++)
#pragma unroll
        for (int j = 0; j < 2; j++)
#pragma unroll
            for (int q = 0; q < 4; q++) {
                int gr = m0 + (wr << 5) + (i << 4) + rq + q;
                int gc = n0 + (wc << 5) + (j << 4) + cc;
                gammaH[((size_t)gr << 10) + gc] = f2bf(expf(-fmaxf(acc[i][j][q] + bdh[gc], 0.f)));
            }
}

__global__ __launch_bounds__(256) void k_beta(const u16* __restrict__ A2_all,
                                              const u16* __restrict__ WwcB,
                                              const float* __restrict__ bwc,
                                              float* __restrict__ beta_all) {
    __shared__ u16 lA[2048], lB[2048];
    int m0 = blockIdx.x << 6, n0 = blockIdx.y << 6;
    f32x4 acc[2][2]; ZACC(acc);
    gemm_loop(A2_all, 512, WwcB, 512, 512, m0, n0, lA, lB, acc);
    int lane = threadIdx.x & 63, wid = threadIdx.x >> 6;
    int wr = wid >> 1, wc = wid & 1;
    int rq = (lane >> 4) << 2, cc = lane & 15;
#pragma unroll
    for (int i = 0; i < 2; i++)
#pragma unroll
        for (int j = 0; j < 2; j++)
#pragma unroll
            for (int q = 0; q < 4; q++) {
                int gr = m0 + (wr << 5) + (i << 4) + rq + q;
                int gc = n0 + (wc << 5) + (j << 4) + cc;
                beta_all[((size_t)gr << 8) + gc] = acc[i][j][q] + bwc[gc];
            }
}

// h init: h = h0 * gammaH(t=0); also seed A3x hbf segment 0 (cols 512..1535)
__global__ void k_hinit(const void* __restrict__ h0, const int* __restrict__ flagp,
                        const u16* __restrict__ gammaH,
                        float* __restrict__ h, u16* __restrict__ A3x) {
    int bf = *flagp;
    int i = blockIdx.x * 256 + threadIdx.x;  // 524288
    float g = bf2f(gammaH[i]);
    float hv = ldin(h0, i, bf) * g;
    h[i] = hv;
    int r = i >> 10, c = i & 1023;
    A3x[(size_t)r * 2560 + 512 + c] = f2bf(hv);
}

// ---- per-step kernel 1: hist GEMM + feature-regression + combine ----
// 32 blocks x 512 threads; block = 16-row stripe, 8 waves x 32 cols
__global__ __launch_bounds__(512) void k_histcomb(
    u16* __restrict__ A3x, const u16* __restrict__ WhB,
    const u16* __restrict__ WfrB, const float* __restrict__ biases,
    const float* __restrict__ beta_all,
    const void* __restrict__ x, const void* __restrict__ mask,
    int t, const int* __restrict__ flagp,
    void* __restrict__ out,
    float* __restrict__ lossN, float* __restrict__ lossD) {
    __shared__ u16 lH[16 * 1032];
    __shared__ u16 lXR[16 * 264];
    __shared__ float redN[8], redD[8];
    int tid = threadIdx.x;
    int m0 = blockIdx.x << 4;
    int lane = tid & 63, w = tid >> 6;
    int lrow = lane & 15, lseg = lane >> 4;
    int c0 = w << 5;
    int bf = *flagp;
    int hoff = 512 + ((t & 1) << 10);

    // stage 16x1024 hbf stripe from A3x (stride 2560)
    {
        int row = tid >> 5;
        int colb = (tid & 31) << 3;
        const u16* src = A3x + (size_t)(m0 + row) * 2560 + hoff;
#pragma unroll
        for (int j = 0; j < 4; ++j) {
            int off = colb + (j << 8);
            *(uint4*)&lH[row * 1032 + off] = *(const uint4*)&src[off];
        }
    }
    __syncthreads();

    // hist: A from LDS, B (Wh) direct global->reg, no barriers
    f32x4 acc[2] = {};
#pragma unroll 4
    for (int k0 = 0; k0 < 1024; k0 += 32) {
        int kk = k0 + (lseg << 3);
        s16x8 a = *(const s16x8*)&lH[lrow * 1032 + kk];
#pragma unroll
        for (int j = 0; j < 2; ++j) {
            s16x8 b = *(const s16x8*)&WhB[((size_t)(c0 + (j << 4) + lrow) << 10) + kk];
            acc[j] = __builtin_amdgcn_mfma_f32_16x16x32_bf16(a, b, acc[j], 0, 0, 0);
        }
    }

    float xhr[2][4], mvr[2][4], xvr[2][4];
#pragma unroll
    for (int j = 0; j < 2; ++j) {
        int gc = c0 + (j << 4) + lrow;
        float bhc = biases[1280 + gc];
#pragma unroll
        for (int q = 0; q < 4; ++q) {
            int r = (lseg << 2) + q;
            float v = acc[j][q] + bhc;
            int gidx = ((m0 + r) << 14) + (t << 8) + gc;
            float mv = ldin(mask, gidx, bf);
            float xv = ldin(x, gidx, bf);
            xhr[j][q] = v; mvr[j][q] = mv; xvr[j][q] = xv;
            lXR[r * 264 + gc] = f2bf(mv * xv + (1.f - mv) * v);
        }
    }
    __syncthreads();

    f32x4 accF[2] = {};
#pragma unroll
    for (int k0 = 0; k0 < 256; k0 += 32) {
        int kk = k0 + (lseg << 3);
        s16x8 a = *(const s16x8*)&lXR[lrow * 264 + kk];
#pragma unroll
        for (int j = 0; j < 2; ++j) {
            s16x8 b = *(const s16x8*)&WfrB[((size_t)(c0 + (j << 4) + lrow) << 8) + kk];
            accF[j] = __builtin_amdgcn_mfma_f32_16x16x32_bf16(a, b, accF[j], 0, 0, 0);
        }
    }

    float ln = 0.f, ldn = 0.f;
#pragma unroll
    for (int j = 0; j < 2; ++j) {
        int gc = c0 + (j << 4) + lrow;
        float bfrc = biases[1536 + gc];
#pragma unroll
        for (int q = 0; q < 4; ++q) {
            int r = (lseg << 2) + q;
            int gr = m0 + r;
            float xu = accF[j][q] + bfrc;
            float beta = beta_all[(((size_t)t * 512 + gr) << 8) + gc];
            float xc = beta * xu + (1.f - beta) * xhr[j][q];
            int gidx = (gr << 14) + (t << 8) + gc;
            float mv = mvr[j][q], xv = xvr[j][q];
            stout(out, OREC + gidx, xc, bf);
            float xi = mv * xv + (1.f - mv) * xc;
            stout(out, gidx, xi, bf);
            A3x[(size_t)gr * 2560 + gc] = f2bf(xi);
            A3x[(size_t)gr * 2560 + 256 + gc] = f2bf(mv);
            ln += fabsf(xc - xv) * mv;
            ldn += mv;
        }
    }
    for (int o = 32; o > 0; o >>= 1) { ln += __shfl_down(ln, o); ldn += __shfl_down(ldn, o); }
    if (lane == 0) { redN[w] = ln; redD[w] = ldn; }
    __syncthreads();
    if (tid == 0) {
        float sn = 0.f, sd = 0.f;
#pragma unroll
        for (int i = 0; i < 8; ++i) { sn += redN[i]; sd += redD[i]; }
        atomicAdd(&lossN[t], sn);
        atomicAdd(&lossD[t], sd);
    }
}

// ---- per-step kernel 2: fused gi+gh GEMM (K=1536) + GRU + next-step decay ----
// 256 blocks x 512 threads, NO LDS, NO barriers. Wave tile 16 rows x 16 hcols x 3 gates.
// bid -> xcd=bid&7, nt = ((bid>>5)<<3)|xcd (0..63, 16 hcols), mg = (bid>>3)&3 (128 rows)
__global__ __launch_bounds__(512) void k_gates3(
    u16* __restrict__ A3x, const u16* __restrict__ W2B,
    const float* __restrict__ biases, const u16* __restrict__ gammaH,
    int t, float* __restrict__ h, void* __restrict__ out,
    const int* __restrict__ flagp) {
    int tid = threadIdx.x, bid = blockIdx.x;
    int xcd = bid & 7, slot = bid >> 3;
    int mg = slot & 3, nt = ((slot >> 2) << 3) | xcd;
    int n0 = nt << 4;
    int w = tid >> 6, lane = tid & 63;
    int lrow = lane & 15, lseg = lane >> 4;
    int m0 = (mg << 7) + (w << 4);
    int hsel = 512 + ((t & 1) << 10);
    int kk = lseg << 3;

    const u16* Ab = A3x + (size_t)(m0 + lrow) * 2560 + kk;
    const u16* BR = W2B + (size_t)(n0 + lrow) * 1536 + kk;
    const u16* BZ = BR + (size_t)1024 * 1536;
    const u16* BN = BZ + (size_t)1024 * 1536;

    f32x4 aR = {0.f, 0.f, 0.f, 0.f}, aZ = {0.f, 0.f, 0.f, 0.f}, aN = {0.f, 0.f, 0.f, 0.f};
#pragma unroll 4
    for (int f = 0; f < 48; ++f) {
        int kA = (f < 16) ? (f << 5) : (hsel + ((f - 16) << 5));
        int kB = f << 5;
        s16x8 a = *(const s16x8*)&Ab[kA];
        s16x8 br = *(const s16x8*)&BR[kB];
        s16x8 bz = *(const s16x8*)&BZ[kB];
        s16x8 bn = *(const s16x8*)&BN[kB];
        aR = __builtin_amdgcn_mfma_f32_16x16x32_bf16(a, br, aR, 0, 0, 0);
        aZ = __builtin_amdgcn_mfma_f32_16x16x32_bf16(a, bz, aZ, 0, 0, 0);
        aN = __builtin_amdgcn_mfma_f32_16x16x32_bf16(a, bn, aN, 0, 0, 0);
    }

    int bf = *flagp;
    int gc = n0 + lrow;
    float bR = biases[2048 + gc] + biases[5120 + gc];
    float bZ2 = biases[3072 + gc] + biases[6144 + gc];
    float bNi = biases[4096 + gc];
    float bNh = biases[7168 + gc];
    int nseg = 512 + (((t + 1) & 1) << 10);
    int last = (t == 63);
#pragma unroll
    for (int q = 0; q < 4; ++q) {
        int gr = m0 + (lseg << 2) + q;
        float rr = 1.f / (1.f + expf(-(aR[q] + bR)));
        float zz = 1.f / (1.f + expf(-(aZ[q] + bZ2)));
        float nn = tanhf(aN[q] + bNi + rr * bNh - rr * bNh + (bNi - bNi));  // placeholder removed below
        (void)nn;
        // NOTE: gh's N-part bias must multiply by r: n = tanh(aNi + bNi + r*(aNh + bNh)).
        // aN here already holds aNi + aNh (single fused accumulation) -- WRONG for N gate.
        int idx = (gr << 10) + gc;
        (void)idx;
    }
    // --- correct N-gate handling: recompute using split accumulation below ---
    // (see aN2 path; this loop intentionally does nothing)
#pragma unroll
    for (int q = 0; q < 4; ++q) { (void)q; }
    // The fused-K trick is invalid for the N gate (r gates the gh part only),
    // so the N gate's gh contribution is accumulated separately:
    f32x4 aN2 = {0.f, 0.f, 0.f, 0.f};
    {
        // subtract: recompute gh-part of N (K = 1024) -- cheap (1/3 of one gate)
        const u16* BNh = BN;
#pragma unroll 4
        for (int f = 16; f < 48; ++f) {
            int kA = hsel + ((f - 16) << 5);
            int kB = f << 5;
            s16x8 a = *(const s16x8*)&Ab[kA];
            s16x8 bn = *(const s16x8*)&BNh[kB];
            aN2 = __builtin_amdgcn_mfma_f32_16x16x32_bf16(a, bn, aN2, 0, 0, 0);
        }
    }
#pragma unroll
    for (int q = 0; q < 4; ++q) {
        int gr = m0 + (lseg << 2) + q;
        float rr = 1.f / (1.f + expf(-(aR[q] + bR)));
        float zz = 1.f / (1.f + expf(-(aZ[q] + bZ2)));
        float ni = aN[q] - aN2[q];            // gi part of N
        float nh = aN2[q];                    // gh part of N
        float nn = tanhf(ni + bNi + rr * (nh + bNh));
        int idx = (gr << 10) + gc;
        float hv = (1.f - zz) * nn + zz * h[idx];
        if (!last) {
            hv *= bf2f(gammaH[((size_t)(t + 1) * 512 + gr) * 1024 + gc]);
            h[idx] = hv;
            A3x[(size_t)gr * 2560 + nseg + gc] = f2bf(hv);
        } else {
            stout(out, OH + idx, hv, bf);
        }
    }
}

// ---- epilogue ----
__global__ void k_loss(const float* __restrict__ lossN, const float* __restrict__ lossD,
                       void* __restrict__ out, const int* __restrict__ flagp) {
    int t = threadIdx.x;  // 64
    float v = lossN[t] / (lossD[t] + 1e-12f);
    for (int o = 32; o > 0; o >>= 1) v += __shfl_down(v, o);
    if (t == 0) {
        int bf = *flagp;
        stout(out, OLOSS, v, bf);
        stout(out, OLOSS + 1, 0.f, bf);
    }
}

extern "C" void kernel_launch(void* const* d_in, const int* in_sizes, int n_in,
                              void* d_out, int out_size, void* d_ws, size_t ws_size,
                              hipStream_t stream) {
    (void)in_sizes; (void)n_in; (void)out_size; (void)ws_size;
    const void* x = d_in[0];
    const void* mask = d_in[1];
    const void* deltas = d_in[2];
    const void* h0 = d_in[3];
    const void* Wdh = d_in[4];  const void* bdh = d_in[5];
    const void* Wdx = d_in[6];  const void* bdx = d_in[7];
    const void* Wh = d_in[8];   const void* bh = d_in[9];
    const void* Wfr = d_in[10]; const void* bfr = d_in[11];
    const void* Wwc = d_in[12]; const void* bwc = d_in[13];
    const void* Wih = d_in[14]; const void* bih = d_in[15];
    const void* Whh = d_in[16]; const void* bhh = d_in[17];

    char* cur = (char*)d_ws;
    auto carve = [&](size_t bytes) -> char* {
        char* p = cur; cur += (bytes + 255) & ~(size_t)255; return p;
    };
    int* flag = (int*)carve(sizeof(int));
    float* lossN = (float*)carve(64 * 4);
    float* lossD = (float*)carve(64 * 4);
    float* wdxd = (float*)carve(256 * 4);
    float* biasesF = (float*)carve(8192 * 4);
    u16* WdhB = (u16*)carve(262144 * 2);
    u16* WhB = (u16*)carve(262144 * 2);
    u16* WfrB = (u16*)carve(65536 * 2);
    u16* WwcB = (u16*)carve(131072 * 2);
    u16* W2B = (u16*)carve((size_t)4718592 * 2);
    float* h = (float*)carve(524288 * 4);
    u16* A3x = (u16*)carve((size_t)512 * 2560 * 2);
    u16* dbf_all = (u16*)carve((size_t)8388608 * 2);
    u16* A2_all = (u16*)carve((size_t)16777216 * 2);
    u16* gammaH_all = (u16*)carve((size_t)33554432 * 2);
    float* beta_all = (float*)carve((size_t)8388608 * 4);

    float* bdhF = biasesF;
    float* bdxF = biasesF + 1024;

    // prologue: dtype detect + weight prep
    k_zero<<<1, 64, 0, stream>>>(flag, lossN, lossD);
    k_detect<<<256, 256, 0, stream>>>((const u32*)mask, flag);
    k_cvt_bf<<<1024, 256, 0, stream>>>(Wdh, WdhB, 262144, flag);
    k_cvt_bf<<<1024, 256, 0, stream>>>(Wh, WhB, 262144, flag);
    k_cvt_bf<<<256, 256, 0, stream>>>(Wfr, WfrB, 65536, flag);
    k_cvt_bf<<<512, 256, 0, stream>>>(Wwc, WwcB, 131072, flag);
    k_packW2<<<3072, 256, 0, stream>>>(Wih, Whh, W2B, flag);
    k_cvt_biases<<<32, 256, 0, stream>>>(bdh, bdx, bh, bfr, bwc, bih, bhh, biasesF, flag);
    k_fixup<<<1, 256, 0, stream>>>(WfrB, wdxd, Wdx, flag);

    // precompute: gamma_x/mask pack, gamma_h for all t, beta for all t
    k_pack<<<8192, 256, 0, stream>>>(deltas, mask, flag, wdxd, bdxF, dbf_all, A2_all);
    k_gammaH<<<dim3(512, 16), 256, 0, stream>>>(dbf_all, WdhB, bdhF, gammaH_all);
    k_beta<<<dim3(512, 4), 256, 0, stream>>>(A2_all, WwcB, biasesF + 1792, beta_all);
    k_hinit<<<2048, 256, 0, stream>>>(h0, flag, gammaH_all, h, A3x);

    for (int t = 0; t < 64; ++t) {
        k_histcomb<<<32, 512, 0, stream>>>(A3x, WhB, WfrB, biasesF, beta_all, x, mask,
                                           t, flag, d_out, lossN, lossD);
        k_gates3<<<256, 512, 0, stream>>>(A3x, W2B, biasesF, gammaH_all, t, h, d_out, flag);
    }
    k_loss<<<1, 64, 0, stream>>>(lossN, lossD, d_out, flag);
}

// Round 6
// 5011.293 us; speedup vs baseline: 1.3232x; 1.1427x over previous
//
#include <hip/hip_runtime.h>
#include <hip/hip_bf16.h>

typedef unsigned short u16;
typedef unsigned int u32;
typedef __attribute__((ext_vector_type(4))) float f32x4;
typedef __attribute__((ext_vector_type(8))) short s16x8;

#define OREC 8388608
#define OH 16777216
#define OLOSS 17301504

__device__ __forceinline__ float bf2f(u16 u) {
    union { u32 i; float f; } v; v.i = ((u32)u) << 16; return v.f;
}
__device__ __forceinline__ u16 f2bf(float f) {
    union { float f; u32 i; } v; v.f = f;
    u32 i = v.i;
    u32 r = i + 0x7FFFu + ((i >> 16) & 1u);
    return (u16)(r >> 16);
}
__device__ __forceinline__ float ldin(const void* p, int i, int bf) {
    return bf ? bf2f(((const u16*)p)[i]) : ((const float*)p)[i];
}
__device__ __forceinline__ void stout(void* p, int i, float v, int bf) {
    if (bf) ((u16*)p)[i] = f2bf(v); else ((float*)p)[i] = v;
}

#define ZACC(A) do { \
    _Pragma("unroll") for (int zi = 0; zi < 2; ++zi) \
    _Pragma("unroll") for (int zj = 0; zj < 2; ++zj) \
    _Pragma("unroll") for (int zq = 0; zq < 4; ++zq) A[zi][zj][zq] = 0.f; \
} while (0)

// ---- legacy 64x64 GEMM core (one-time gammaH/beta precompute) ----
__device__ __forceinline__ void stage_tile(const u16* __restrict__ src, int ld, int row0, int k0,
                                           u16* lds) {
    int t = threadIdx.x;
    int row = t >> 2, seg = t & 3;
    const u16* g = src + (size_t)(row0 + row) * ld + k0 + (seg << 3);
    uint4 v = *(const uint4*)g;
    *(uint4*)&lds[(row << 5) + ((seg ^ (row & 3)) << 3)] = v;
}

__device__ __forceinline__ void gemm_loop(const u16* __restrict__ A, int lda,
                                          const u16* __restrict__ W, int ldw,
                                          int K, int m0, int n0,
                                          u16* lA, u16* lB, f32x4 acc[2][2]) {
    int lane = threadIdx.x & 63;
    int wid = threadIdx.x >> 6;
    int wr = wid >> 1, wc = wid & 1;
    int lrow = lane & 15, lseg = lane >> 4;
    int sw = (lseg ^ (lrow & 3)) << 3;
    for (int k0 = 0; k0 < K; k0 += 32) {
        __syncthreads();
        stage_tile(A, lda, m0, k0, lA);
        stage_tile(W, ldw, n0, k0, lB);
        __syncthreads();
        s16x8 af[2], bg[2];
#pragma unroll
        for (int i = 0; i < 2; i++) {
            int r = (wr << 5) + (i << 4) + lrow;
            af[i] = *(const s16x8*)&lA[(r << 5) + sw];
            int c = (wc << 5) + (i << 4) + lrow;
            bg[i] = *(const s16x8*)&lB[(c << 5) + sw];
        }
#pragma unroll
        for (int i = 0; i < 2; i++)
#pragma unroll
            for (int j = 0; j < 2; j++)
                acc[i][j] = __builtin_amdgcn_mfma_f32_16x16x32_bf16(af[i], bg[j], acc[i][j], 0, 0, 0);
    }
}

// ---- prologue kernels ----
__global__ void k_zero(int* flag, float* lossN, float* lossD) {
    if (threadIdx.x == 0) *flag = 0;
    if (threadIdx.x < 64) { lossN[threadIdx.x] = 0.f; lossD[threadIdx.x] = 0.f; }
}

__global__ void k_detect(const u32* __restrict__ w, int* flag) {
    int gid = blockIdx.x * 256 + threadIdx.x;
    int found = 0;
    for (int i = gid; i < (1 << 20); i += 65536) {
        if ((w[i] & 0xFFFFu) == 0x3F80u) found = 1;
    }
    if (found) atomicOr(flag, 1);
}

__global__ void k_cvt_bf(const void* __restrict__ src, u16* __restrict__ dst, int n,
                         const int* __restrict__ flagp) {
    int bf = *flagp;
    for (int i = blockIdx.x * 256 + threadIdx.x; i < n; i += gridDim.x * 256)
        dst[i] = bf ? ((const u16*)src)[i] : f2bf(((const float*)src)[i]);
}

// W2[c][k] : k<512 -> Wih[c][k]; else Whh[c][k-512].  c in [0,3072), ld 1536
__global__ void k_packW2(const void* __restrict__ Wih, const void* __restrict__ Whh,
                         u16* __restrict__ W2B, const int* __restrict__ flagp) {
    int bf = *flagp;
    int c = blockIdx.x;       // 3072
    int k0 = threadIdx.x;     // 256
#pragma unroll
    for (int j = 0; j < 6; ++j) {
        int k = k0 + (j << 8);
        float v = (k < 512) ? ldin(Wih, c * 512 + k, bf)
                            : ldin(Whh, c * 1024 + (k - 512), bf);
        W2B[(size_t)c * 1536 + k] = f2bf(v);
    }
}

// merged bias conversion: [0,1024)=bdh [1024,1280)=bdx [1280,1536)=bh
// [1536,1792)=bfr [1792,2048)=bwc [2048,5120)=bih [5120,8192)=bhh
__global__ void k_cvt_biases(const void* __restrict__ bdh, const void* __restrict__ bdx,
                             const void* __restrict__ bh, const void* __restrict__ bfr,
                             const void* __restrict__ bwc, const void* __restrict__ bih,
                             const void* __restrict__ bhh, float* __restrict__ dst,
                             const int* __restrict__ flagp) {
    int bf = *flagp;
    int i = blockIdx.x * 256 + threadIdx.x;  // 8192
    const void* src; int off;
    if (i < 1024) { src = bdh; off = 0; }
    else if (i < 1280) { src = bdx; off = 1024; }
    else if (i < 1536) { src = bh; off = 1280; }
    else if (i < 1792) { src = bfr; off = 1536; }
    else if (i < 2048) { src = bwc; off = 1792; }
    else if (i < 5120) { src = bih; off = 2048; }
    else { src = bhh; off = 5120; }
    dst[i] = ldin(src, i - off, bf);
}

__global__ void k_fixup(u16* __restrict__ WfrB, float* __restrict__ wdxd,
                        const void* __restrict__ Wdx, const int* __restrict__ flagp) {
    int f = threadIdx.x;  // 256
    int bf = *flagp;
    WfrB[f * 256 + f] = 0;
    wdxd[f] = ldin(Wdx, f * 257, bf);
}

// ---- precompute kernels ----
__global__ void k_pack(const void* __restrict__ deltas, const void* __restrict__ mask,
                       const int* __restrict__ flagp,
                       const float* __restrict__ wdxd, const float* __restrict__ bdx,
                       u16* __restrict__ dbf_all, u16* __restrict__ A2_all) {
    int bf = *flagp;
    for (int idx = blockIdx.x * 256 + threadIdx.x; idx < 8388608; idx += gridDim.x * 256) {
        int f = idx & 255;
        int bt = idx >> 8;
        int b = bt >> 6, t = bt & 63;
        float d = ldin(deltas, idx, bf);
        float m = ldin(mask, idx, bf);
        int r = t * 512 + b;
        dbf_all[(r << 8) + f] = f2bf(d);
        float gx = expf(-fmaxf(d * wdxd[f] + bdx[f], 0.f));
        A2_all[(r << 9) + f] = f2bf(gx);
        A2_all[(r << 9) + 256 + f] = f2bf(m);
    }
}

__global__ __launch_bounds__(256) void k_gammaH(const u16* __restrict__ dbf_all,
                                                const u16* __restrict__ WdhB,
                                                const float* __restrict__ bdh,
                                                u16* __restrict__ gammaH) {
    __shared__ u16 lA[2048], lB[2048];
    int m0 = blockIdx.x << 6, n0 = blockIdx.y << 6;
    f32x4 acc[2][2]; ZACC(acc);
    gemm_loop(dbf_all, 256, WdhB, 256, 256, m0, n0, lA, lB, acc);
    int lane = threadIdx.x & 63, wid = threadIdx.x >> 6;
    int wr = wid >> 1, wc = wid & 1;
    int rq = (lane >> 4) << 2, cc = lane & 15;
#pragma unroll
    for (int i = 0; i < 2; i++)
#pragma unroll
        for (int j = 0; j < 2; j++)
#pragma unroll
            for (int q = 0; q < 4; q++) {
                int gr = m0 + (wr << 5) + (i << 4) + rq + q;
                int gc = n0 + (wc << 5) + (j << 4) + cc;
                gammaH[((size_t)gr << 10) + gc] = f2bf(expf(-fmaxf(acc[i][j][q] + bdh[gc], 0.f)));
            }
}

__global__ __launch_bounds__(256) void k_beta(const u16* __restrict__ A2_all,
                                              const u16* __restrict__ WwcB,
                                              const float* __restrict__ bwc,
                                              float* __restrict__ beta_all) {
    __shared__ u16 lA[2048], lB[2048];
    int m0 = blockIdx.x << 6, n0 = blockIdx.y << 6;
    f32x4 acc[2][2]; ZACC(acc);
    gemm_loop(A2_all, 512, WwcB, 512, 512, m0, n0, lA, lB, acc);
    int lane = threadIdx.x & 63, wid = threadIdx.x >> 6;
    int wr = wid >> 1, wc = wid & 1;
    int rq = (lane >> 4) << 2, cc = lane & 15;
#pragma unroll
    for (int i = 0; i < 2; i++)
#pragma unroll
        for (int j = 0; j < 2; j++)
#pragma unroll
            for (int q = 0; q < 4; q++) {
                int gr = m0 + (wr << 5) + (i << 4) + rq + q;
                int gc = n0 + (wc << 5) + (j << 4) + cc;
                beta_all[((size_t)gr << 8) + gc] = acc[i][j][q] + bwc[gc];
            }
}

// h init: hseg0 = h0 * gammaH(t=0)  (bf16, A3x cols 512..1535)
__global__ void k_hinit(const void* __restrict__ h0, const int* __restrict__ flagp,
                        const u16* __restrict__ gammaH, u16* __restrict__ A3x) {
    int bf = *flagp;
    int i = blockIdx.x * 256 + threadIdx.x;  // 524288
    float g = bf2f(gammaH[i]);
    float hv = ldin(h0, i, bf) * g;
    int r = i >> 10, c = i & 1023;
    A3x[(size_t)r * 2560 + 512 + c] = f2bf(hv);
}

// ---- per-step kernel 1: GRU-finish(prev step) + hist + feature-reg + combine ----
// 32 blocks x 512 threads; block = 16-row stripe
__global__ __launch_bounds__(512) void k_histcomb2(
    u16* __restrict__ A3x, const float* __restrict__ pbuf,
    const u16* __restrict__ WhB, const u16* __restrict__ WfrB,
    const float* __restrict__ biases, const float* __restrict__ beta_all,
    const u16* __restrict__ gammaH,
    const void* __restrict__ x, const void* __restrict__ mask,
    int t, const int* __restrict__ flagp,
    void* __restrict__ out, float* __restrict__ lossN, float* __restrict__ lossD) {
    __shared__ u16 lH[16 * 1032];
    __shared__ u16 lXR[16 * 264];
    __shared__ float redN[8], redD[8];
    int tid = threadIdx.x;
    int m0 = blockIdx.x << 4;
    int lane = tid & 63, w = tid >> 6;
    int lrow = lane & 15, lseg = lane >> 4;
    int c0 = w << 5;
    int bf = *flagp;
    int curseg = 512 + ((t & 1) << 10);

    if (t == 0) {
        // stage hd(0) written by k_hinit
        int row = tid >> 5;
        int colb = (tid & 31) << 3;
        const u16* src = A3x + (size_t)(m0 + row) * 2560 + curseg;
#pragma unroll
        for (int j = 0; j < 4; ++j) {
            int off = colb + (j << 8);
            *(uint4*)&lH[row * 1032 + off] = *(const uint4*)&src[off];
        }
    } else {
        // GRU finish for step t-1, then decay by gammaH(t): hd(t)
        int prevseg = 512 + (((t - 1) & 1) << 10);
        int r = tid >> 5, cb = tid & 31;
        int gr = m0 + r;
        const float* p0 = pbuf + (size_t)gr * 3072;
        const float* p1 = pbuf + (size_t)512 * 3072 + (size_t)gr * 3072;
        const u16* hps = A3x + (size_t)gr * 2560 + prevseg;
        const u16* gms = gammaH + (((size_t)t * 512 + gr) << 10);
        u16* hcs = A3x + (size_t)gr * 2560 + curseg;
#pragma unroll 4
        for (int j = 0; j < 32; ++j) {
            int c = cb + (j << 5);
            float rr = 1.f / (1.f + expf(-(p0[c] + p1[c] + biases[2048 + c] + biases[5120 + c])));
            float zz = 1.f / (1.f + expf(-(p0[1024 + c] + p1[1024 + c] + biases[3072 + c] + biases[6144 + c])));
            float nn = tanhf(p0[2048 + c] + biases[4096 + c] + rr * (p1[2048 + c] + biases[7168 + c]));
            float hp = bf2f(hps[c]);
            float hun = (1.f - zz) * nn + zz * hp;
            float hd = hun * bf2f(gms[c]);
            u16 hb = f2bf(hd);
            lH[r * 1032 + c] = hb;
            hcs[c] = hb;
        }
    }
    __syncthreads();

    // hist: A from LDS, B (Wh) direct global->reg
    f32x4 acc[2] = {};
#pragma unroll 4
    for (int k0 = 0; k0 < 1024; k0 += 32) {
        int kk = k0 + (lseg << 3);
        s16x8 a = *(const s16x8*)&lH[lrow * 1032 + kk];
#pragma unroll
        for (int j = 0; j < 2; ++j) {
            s16x8 b = *(const s16x8*)&WhB[((size_t)(c0 + (j << 4) + lrow) << 10) + kk];
            acc[j] = __builtin_amdgcn_mfma_f32_16x16x32_bf16(a, b, acc[j], 0, 0, 0);
        }
    }

    float xhr[2][4], mvr[2][4], xvr[2][4];
#pragma unroll
    for (int j = 0; j < 2; ++j) {
        int gc = c0 + (j << 4) + lrow;
        float bhc = biases[1280 + gc];
#pragma unroll
        for (int q = 0; q < 4; ++q) {
            int r = (lseg << 2) + q;
            float v = acc[j][q] + bhc;
            int gidx = ((m0 + r) << 14) + (t << 8) + gc;
            float mv = ldin(mask, gidx, bf);
            float xv = ldin(x, gidx, bf);
            xhr[j][q] = v; mvr[j][q] = mv; xvr[j][q] = xv;
            lXR[r * 264 + gc] = f2bf(mv * xv + (1.f - mv) * v);
        }
    }
    __syncthreads();

    f32x4 accF[2] = {};
#pragma unroll
    for (int k0 = 0; k0 < 256; k0 += 32) {
        int kk = k0 + (lseg << 3);
        s16x8 a = *(const s16x8*)&lXR[lrow * 264 + kk];
#pragma unroll
        for (int j = 0; j < 2; ++j) {
            s16x8 b = *(const s16x8*)&WfrB[((size_t)(c0 + (j << 4) + lrow) << 8) + kk];
            accF[j] = __builtin_amdgcn_mfma_f32_16x16x32_bf16(a, b, accF[j], 0, 0, 0);
        }
    }

    float ln = 0.f, ldn = 0.f;
#pragma unroll
    for (int j = 0; j < 2; ++j) {
        int gc = c0 + (j << 4) + lrow;
        float bfrc = biases[1536 + gc];
#pragma unroll
        for (int q = 0; q < 4; ++q) {
            int r = (lseg << 2) + q;
            int gr = m0 + r;
            float xu = accF[j][q] + bfrc;
            float beta = beta_all[(((size_t)t * 512 + gr) << 8) + gc];
            float xc = beta * xu + (1.f - beta) * xhr[j][q];
            int gidx = (gr << 14) + (t << 8) + gc;
            float mv = mvr[j][q], xv = xvr[j][q];
            stout(out, OREC + gidx, xc, bf);
            float xi = mv * xv + (1.f - mv) * xc;
            stout(out, gidx, xi, bf);
            A3x[(size_t)gr * 2560 + gc] = f2bf(xi);
            A3x[(size_t)gr * 2560 + 256 + gc] = f2bf(mv);
            ln += fabsf(xc - xv) * mv;
            ldn += mv;
        }
    }
    for (int o = 32; o > 0; o >>= 1) { ln += __shfl_down(ln, o); ldn += __shfl_down(ldn, o); }
    if (lane == 0) { redN[w] = ln; redD[w] = ldn; }
    __syncthreads();
    if (tid == 0) {
        float sn = 0.f, sd = 0.f;
#pragma unroll
        for (int i = 0; i < 8; ++i) { sn += redN[i]; sd += redD[i]; }
        atomicAdd(&lossN[t], sn);
        atomicAdd(&lossD[t], sd);
    }
}

// ---- per-step kernel 2: split-K gates GEMM -> pbuf partials ----
// grid (16 m, 16 n, 2 split); block 512 thr = 8 waves; tile 32 rows x 64 hcols x 3 gates
// split 0: gi (A3x cols 0..511, W2 cols 0..511, K=512)
// split 1: gh (A3x cols hsel.., W2 cols 512.., K=1024)
__global__ __launch_bounds__(512) void k_gates4(
    const u16* __restrict__ A3x, const u16* __restrict__ W2B,
    int t, float* __restrict__ pbuf) {
    __shared__ u16 lds[2 * 8960];   // per buf: B 192 rows x 40 + A 32 rows x 40
    int tid = threadIdx.x;
    int m0 = blockIdx.x << 5, n0 = blockIdx.y << 6;
    int z = blockIdx.z;
    int lane = tid & 63, w = tid >> 6;
    int wr = w & 1, wc = w >> 1;
    int lrow = lane & 15, lseg = lane >> 4;
    int nch = z ? 32 : 16;
    int acol0 = z ? (512 + ((t & 1) << 10)) : 0;
    int bcol0 = z ? 512 : 0;

    // load mapping (2 rounds):
    // r0: t<512 -> B row t>>2 (0..127), seg t&3
    // r1: t<256 -> B row 128+(t>>2), seg t&3 ; 256<=t<384 -> A row (t-256)>>2, seg t&3
    int br0 = tid >> 2, sg0 = tid & 3;
    int g0 = br0 >> 6;
    const u16* Bg0 = W2B + (size_t)(g0 * 1024 + n0 + (br0 & 63)) * 1536 + bcol0 + (sg0 << 3);
    int isB1 = (tid < 256), isA1 = (tid >= 256 && tid < 384);
    int br1 = 128 + (tid >> 2);
    const u16* Bg1 = W2B + (size_t)(2 * 1024 + n0 + (br1 & 63)) * 1536 + bcol0 + (sg0 << 3);
    int ar1 = (tid - 256) >> 2, sg1 = tid & 3;
    const u16* Ag1 = A3x + (size_t)(m0 + ar1) * 2560 + acol0 + (sg1 << 3);

    uint4 p0, p1;
    auto issue = [&](int it) {
        int ko = it << 5;
        p0 = *(const uint4*)(Bg0 + ko);
        if (isB1) p1 = *(const uint4*)(Bg1 + ko);
        else if (isA1) p1 = *(const uint4*)(Ag1 + ko);
    };
    auto store = [&](u16* lb) {
        *(uint4*)&lb[br0 * 40 + (sg0 << 3)] = p0;
        if (isB1) *(uint4*)&lb[br1 * 40 + (sg0 << 3)] = p1;
        else if (isA1) *(uint4*)&lb[7680 + ar1 * 40 + (sg1 << 3)] = p1;
    };

    f32x4 aR = {0.f, 0.f, 0.f, 0.f}, aZ = {0.f, 0.f, 0.f, 0.f}, aN = {0.f, 0.f, 0.f, 0.f};
    issue(0);
    store(lds);
    __syncthreads();
    int cur = 0;
#pragma unroll 1
    for (int it = 0; it < nch; ++it) {
        if (it + 1 < nch) issue(it + 1);
        u16* lc = lds + (cur ? 8960 : 0);
        s16x8 a = *(const s16x8*)&lc[7680 + ((wr << 4) + lrow) * 40 + (lseg << 3)];
        int bro = ((wc << 4) + lrow) * 40 + (lseg << 3);
        s16x8 b0 = *(const s16x8*)&lc[bro];
        aR = __builtin_amdgcn_mfma_f32_16x16x32_bf16(a, b0, aR, 0, 0, 0);
        s16x8 b1 = *(const s16x8*)&lc[2560 + bro];
        aZ = __builtin_amdgcn_mfma_f32_16x16x32_bf16(a, b1, aZ, 0, 0, 0);
        s16x8 b2 = *(const s16x8*)&lc[5120 + bro];
        aN = __builtin_amdgcn_mfma_f32_16x16x32_bf16(a, b2, aN, 0, 0, 0);
        if (it + 1 < nch) store(lds + (cur ? 0 : 8960));
        __syncthreads();
        cur ^= 1;
    }

    float* pb = pbuf + (size_t)z * 512 * 3072;
    int colR = n0 + (wc << 4) + lrow;
#pragma unroll
    for (int q = 0; q < 4; ++q) {
        int row = m0 + (wr << 4) + (lseg << 2) + q;
        float* pr = pb + (size_t)row * 3072 + colR;
        pr[0] = aR[q];
        pr[1024] = aZ[q];
        pr[2048] = aN[q];
    }
}

// ---- final h: GRU finish of step 63, undecayed, -> OH ----
__global__ void k_hfinal(const float* __restrict__ pbuf, const u16* __restrict__ A3x,
                         const float* __restrict__ biases, void* __restrict__ out,
                         const int* __restrict__ flagp) {
    int bf = *flagp;
    int i = blockIdx.x * 256 + threadIdx.x;  // 524288
    int gr = i >> 10, c = i & 1023;
    const float* p0 = pbuf + (size_t)gr * 3072;
    const float* p1 = pbuf + (size_t)512 * 3072 + (size_t)gr * 3072;
    float rr = 1.f / (1.f + expf(-(p0[c] + p1[c] + biases[2048 + c] + biases[5120 + c])));
    float zz = 1.f / (1.f + expf(-(p0[1024 + c] + p1[1024 + c] + biases[3072 + c] + biases[6144 + c])));
    float nn = tanhf(p0[2048 + c] + biases[4096 + c] + rr * (p1[2048 + c] + biases[7168 + c]));
    float hp = bf2f(A3x[(size_t)gr * 2560 + 512 + 1024 + c]);  // seg of t=63
    float hv = (1.f - zz) * nn + zz * hp;
    stout(out, OH + i, hv, bf);
}

// ---- epilogue ----
__global__ void k_loss(const float* __restrict__ lossN, const float* __restrict__ lossD,
                       void* __restrict__ out, const int* __restrict__ flagp) {
    int t = threadIdx.x;  // 64
    float v = lossN[t] / (lossD[t] + 1e-12f);
    for (int o = 32; o > 0; o >>= 1) v += __shfl_down(v, o);
    if (t == 0) {
        int bf = *flagp;
        stout(out, OLOSS, v, bf);
        stout(out, OLOSS + 1, 0.f, bf);
    }
}

extern "C" void kernel_launch(void* const* d_in, const int* in_sizes, int n_in,
                              void* d_out, int out_size, void* d_ws, size_t ws_size,
                              hipStream_t stream) {
    (void)in_sizes; (void)n_in; (void)out_size; (void)ws_size;
    const void* x = d_in[0];
    const void* mask = d_in[1];
    const void* deltas = d_in[2];
    const void* h0 = d_in[3];
    const void* Wdh = d_in[4];  const void* bdh = d_in[5];
    const void* Wdx = d_in[6];  const void* bdx = d_in[7];
    const void* Wh = d_in[8];   const void* bh = d_in[9];
    const void* Wfr = d_in[10]; const void* bfr = d_in[11];
    const void* Wwc = d_in[12]; const void* bwc = d_in[13];
    const void* Wih = d_in[14]; const void* bih = d_in[15];
    const void* Whh = d_in[16]; const void* bhh = d_in[17];

    char* cur = (char*)d_ws;
    auto carve = [&](size_t bytes) -> char* {
        char* p = cur; cur += (bytes + 255) & ~(size_t)255; return p;
    };
    int* flag = (int*)carve(sizeof(int));
    float* lossN = (float*)carve(64 * 4);
    float* lossD = (float*)carve(64 * 4);
    float* wdxd = (float*)carve(256 * 4);
    float* biasesF = (float*)carve(8192 * 4);
    u16* WdhB = (u16*)carve(262144 * 2);
    u16* WhB = (u16*)carve(262144 * 2);
    u16* WfrB = (u16*)carve(65536 * 2);
    u16* WwcB = (u16*)carve(131072 * 2);
    u16* W2B = (u16*)carve((size_t)4718592 * 2);
    u16* A3x = (u16*)carve((size_t)512 * 2560 * 2);
    float* pbuf = (float*)carve((size_t)2 * 512 * 3072 * 4);
    u16* dbf_all = (u16*)carve((size_t)8388608 * 2);
    u16* A2_all = (u16*)carve((size_t)16777216 * 2);
    u16* gammaH_all = (u16*)carve((size_t)33554432 * 2);
    float* beta_all = (float*)carve((size_t)8388608 * 4);

    float* bdhF = biasesF;
    float* bdxF = biasesF + 1024;

    // prologue: dtype detect + weight prep
    k_zero<<<1, 64, 0, stream>>>(flag, lossN, lossD);
    k_detect<<<256, 256, 0, stream>>>((const u32*)mask, flag);
    k_cvt_bf<<<1024, 256, 0, stream>>>(Wdh, WdhB, 262144, flag);
    k_cvt_bf<<<1024, 256, 0, stream>>>(Wh, WhB, 262144, flag);
    k_cvt_bf<<<256, 256, 0, stream>>>(Wfr, WfrB, 65536, flag);
    k_cvt_bf<<<512, 256, 0, stream>>>(Wwc, WwcB, 131072, flag);
    k_packW2<<<3072, 256, 0, stream>>>(Wih, Whh, W2B, flag);
    k_cvt_biases<<<32, 256, 0, stream>>>(bdh, bdx, bh, bfr, bwc, bih, bhh, biasesF, flag);
    k_fixup<<<1, 256, 0, stream>>>(WfrB, wdxd, Wdx, flag);

    // precompute: gamma_x/mask pack, gamma_h for all t, beta for all t, h init
    k_pack<<<8192, 256, 0, stream>>>(deltas, mask, flag, wdxd, bdxF, dbf_all, A2_all);
    k_gammaH<<<dim3(512, 16), 256, 0, stream>>>(dbf_all, WdhB, bdhF, gammaH_all);
    k_beta<<<dim3(512, 4), 256, 0, stream>>>(A2_all, WwcB, biasesF + 1792, beta_all);
    k_hinit<<<2048, 256, 0, stream>>>(h0, flag, gammaH_all, A3x);

    for (int t = 0; t < 64; ++t) {
        k_histcomb2<<<32, 512, 0, stream>>>(A3x, pbuf, WhB, WfrB, biasesF, beta_all,
                                            gammaH_all, x, mask, t, flag, d_out, lossN, lossD);
        k_gates4<<<dim3(16, 16, 2), 512, 0, stream>>>(A3x, W2B, t, pbuf);
    }
    k_hfinal<<<2048, 256, 0, stream>>>(pbuf, A3x, biasesF, d_out, flag);
    k_loss<<<1, 64, 0, stream>>>(lossN, lossD, d_out, flag);
}

// Round 7
// 3184.385 us; speedup vs baseline: 2.0823x; 1.5737x over previous
//
#include <hip/hip_runtime.h>
#include <hip/hip_bf16.h>

typedef unsigned short u16;
typedef unsigned int u32;
typedef __attribute__((ext_vector_type(4))) float f32x4;
typedef __attribute__((ext_vector_type(8))) short s16x8;

#define OREC 8388608
#define OH 16777216
#define OLOSS 17301504

__device__ __forceinline__ float bf2f(u16 u) {
    union { u32 i; float f; } v; v.i = ((u32)u) << 16; return v.f;
}
__device__ __forceinline__ u16 f2bf(float f) {
    union { float f; u32 i; } v; v.f = f;
    u32 i = v.i;
    u32 r = i + 0x7FFFu + ((i >> 16) & 1u);
    return (u16)(r >> 16);
}
__device__ __forceinline__ float ldin(const void* p, int i, int bf) {
    return bf ? bf2f(((const u16*)p)[i]) : ((const float*)p)[i];
}
__device__ __forceinline__ void stout(void* p, int i, float v, int bf) {
    if (bf) ((u16*)p)[i] = f2bf(v); else ((float*)p)[i] = v;
}

#define ZACC(A) do { \
    _Pragma("unroll") for (int zi = 0; zi < 2; ++zi) \
    _Pragma("unroll") for (int zj = 0; zj < 2; ++zj) \
    _Pragma("unroll") for (int zq = 0; zq < 4; ++zq) A[zi][zj][zq] = 0.f; \
} while (0)

// ---- legacy 64x64 GEMM core (one-time gammaH/beta precompute) ----
__device__ __forceinline__ void stage_tile(const u16* __restrict__ src, int ld, int row0, int k0,
                                           u16* lds) {
    int t = threadIdx.x;
    int row = t >> 2, seg = t & 3;
    const u16* g = src + (size_t)(row0 + row) * ld + k0 + (seg << 3);
    uint4 v = *(const uint4*)g;
    *(uint4*)&lds[(row << 5) + ((seg ^ (row & 3)) << 3)] = v;
}

__device__ __forceinline__ void gemm_loop(const u16* __restrict__ A, int lda,
                                          const u16* __restrict__ W, int ldw,
                                          int K, int m0, int n0,
                                          u16* lA, u16* lB, f32x4 acc[2][2]) {
    int lane = threadIdx.x & 63;
    int wid = threadIdx.x >> 6;
    int wr = wid >> 1, wc = wid & 1;
    int lrow = lane & 15, lseg = lane >> 4;
    int sw = (lseg ^ (lrow & 3)) << 3;
    for (int k0 = 0; k0 < K; k0 += 32) {
        __syncthreads();
        stage_tile(A, lda, m0, k0, lA);
        stage_tile(W, ldw, n0, k0, lB);
        __syncthreads();
        s16x8 af[2], bg[2];
#pragma unroll
        for (int i = 0; i < 2; i++) {
            int r = (wr << 5) + (i << 4) + lrow;
            af[i] = *(const s16x8*)&lA[(r << 5) + sw];
            int c = (wc << 5) + (i << 4) + lrow;
            bg[i] = *(const s16x8*)&lB[(c << 5) + sw];
        }
#pragma unroll
        for (int i = 0; i < 2; i++)
#pragma unroll
            for (int j = 0; j < 2; j++)
                acc[i][j] = __builtin_amdgcn_mfma_f32_16x16x32_bf16(af[i], bg[j], acc[i][j], 0, 0, 0);
    }
}

// ---- prologue kernels ----
__global__ void k_zero(int* flag, float* lossN, float* lossD) {
    if (threadIdx.x == 0) *flag = 0;
    if (threadIdx.x < 64) { lossN[threadIdx.x] = 0.f; lossD[threadIdx.x] = 0.f; }
}

__global__ void k_detect(const u32* __restrict__ w, int* flag) {
    int gid = blockIdx.x * 256 + threadIdx.x;
    int found = 0;
    for (int i = gid; i < (1 << 20); i += 65536) {
        if ((w[i] & 0xFFFFu) == 0x3F80u) found = 1;
    }
    if (found) atomicOr(flag, 1);
}

__global__ void k_cvt_bf(const void* __restrict__ src, u16* __restrict__ dst, int n,
                         const int* __restrict__ flagp) {
    int bf = *flagp;
    for (int i = blockIdx.x * 256 + threadIdx.x; i < n; i += gridDim.x * 256)
        dst[i] = bf ? ((const u16*)src)[i] : f2bf(((const float*)src)[i]);
}

// W2[c][k] : k<512 -> Wih[c][k]; else Whh[c][k-512].  c in [0,3072), ld 1536
__global__ void k_packW2(const void* __restrict__ Wih, const void* __restrict__ Whh,
                         u16* __restrict__ W2B, const int* __restrict__ flagp) {
    int bf = *flagp;
    int c = blockIdx.x;       // 3072
    int k0 = threadIdx.x;     // 256
#pragma unroll
    for (int j = 0; j < 6; ++j) {
        int k = k0 + (j << 8);
        float v = (k < 512) ? ldin(Wih, c * 512 + k, bf)
                            : ldin(Whh, c * 1024 + (k - 512), bf);
        W2B[(size_t)c * 1536 + k] = f2bf(v);
    }
}

// merged bias conversion: [0,1024)=bdh [1024,1280)=bdx [1280,1536)=bh
// [1536,1792)=bfr [1792,2048)=bwc [2048,5120)=bih [5120,8192)=bhh
__global__ void k_cvt_biases(const void* __restrict__ bdh, const void* __restrict__ bdx,
                             const void* __restrict__ bh, const void* __restrict__ bfr,
                             const void* __restrict__ bwc, const void* __restrict__ bih,
                             const void* __restrict__ bhh, float* __restrict__ dst,
                             const int* __restrict__ flagp) {
    int bf = *flagp;
    int i = blockIdx.x * 256 + threadIdx.x;  // 8192
    const void* src; int off;
    if (i < 1024) { src = bdh; off = 0; }
    else if (i < 1280) { src = bdx; off = 1024; }
    else if (i < 1536) { src = bh; off = 1280; }
    else if (i < 1792) { src = bfr; off = 1536; }
    else if (i < 2048) { src = bwc; off = 1792; }
    else if (i < 5120) { src = bih; off = 2048; }
    else { src = bhh; off = 5120; }
    dst[i] = ldin(src, i - off, bf);
}

__global__ void k_fixup(u16* __restrict__ WfrB, float* __restrict__ wdxd,
                        const void* __restrict__ Wdx, const int* __restrict__ flagp) {
    int f = threadIdx.x;  // 256
    int bf = *flagp;
    WfrB[f * 256 + f] = 0;
    wdxd[f] = ldin(Wdx, f * 257, bf);
}

// ---- precompute kernels ----
__global__ void k_pack(const void* __restrict__ deltas, const void* __restrict__ mask,
                       const int* __restrict__ flagp,
                       const float* __restrict__ wdxd, const float* __restrict__ bdx,
                       u16* __restrict__ dbf_all, u16* __restrict__ A2_all) {
    int bf = *flagp;
    for (int idx = blockIdx.x * 256 + threadIdx.x; idx < 8388608; idx += gridDim.x * 256) {
        int f = idx & 255;
        int bt = idx >> 8;
        int b = bt >> 6, t = bt & 63;
        float d = ldin(deltas, idx, bf);
        float m = ldin(mask, idx, bf);
        int r = t * 512 + b;
        dbf_all[(r << 8) + f] = f2bf(d);
        float gx = expf(-fmaxf(d * wdxd[f] + bdx[f], 0.f));
        A2_all[(r << 9) + f] = f2bf(gx);
        A2_all[(r << 9) + 256 + f] = f2bf(m);
    }
}

__global__ __launch_bounds__(256) void k_gammaH(const u16* __restrict__ dbf_all,
                                                const u16* __restrict__ WdhB,
                                                const float* __restrict__ bdh,
                                                u16* __restrict__ gammaH) {
    __shared__ u16 lA[2048], lB[2048];
    int m0 = blockIdx.x << 6, n0 = blockIdx.y << 6;
    f32x4 acc[2][2]; ZACC(acc);
    gemm_loop(dbf_all, 256, WdhB, 256, 256, m0, n0, lA, lB, acc);
    int lane = threadIdx.x & 63, wid = threadIdx.x >> 6;
    int wr = wid >> 1, wc = wid & 1;
    int rq = (lane >> 4) << 2, cc = lane & 15;
#pragma unroll
    for (int i = 0; i < 2; i++)
#pragma unroll
        for (int j = 0; j < 2; j++)
#pragma unroll
            for (int q = 0; q < 4; q++) {
                int gr = m0 + (wr << 5) + (i << 4) + rq + q;
                int gc = n0 + (wc << 5) + (j << 4) + cc;
                gammaH[((size_t)gr << 10) + gc] = f2bf(expf(-fmaxf(acc[i][j][q] + bdh[gc], 0.f)));
            }
}

__global__ __launch_bounds__(256) void k_beta(const u16* __restrict__ A2_all,
                                              const u16* __restrict__ WwcB,
                                              const float* __restrict__ bwc,
                                              float* __restrict__ beta_all) {
    __shared__ u16 lA[2048], lB[2048];
    int m0 = blockIdx.x << 6, n0 = blockIdx.y << 6;
    f32x4 acc[2][2]; ZACC(acc);
    gemm_loop(A2_all, 512, WwcB, 512, 512, m0, n0, lA, lB, acc);
    int lane = threadIdx.x & 63, wid = threadIdx.x >> 6;
    int wr = wid >> 1, wc = wid & 1;
    int rq = (lane >> 4) << 2, cc = lane & 15;
#pragma unroll
    for (int i = 0; i < 2; i++)
#pragma unroll
        for (int j = 0; j < 2; j++)
#pragma unroll
            for (int q = 0; q < 4; q++) {
                int gr = m0 + (wr << 5) + (i << 4) + rq + q;
                int gc = n0 + (wc << 5) + (j << 4) + cc;
                beta_all[((size_t)gr << 8) + gc] = acc[i][j][q] + bwc[gc];
            }
}

// h init: hseg(t=0) = h0 * gammaH(t=0)  (bf16, A3x cols 512..1535)
__global__ void k_hinit(const void* __restrict__ h0, const int* __restrict__ flagp,
                        const u16* __restrict__ gammaH, u16* __restrict__ A3x) {
    int bf = *flagp;
    int i = blockIdx.x * 256 + threadIdx.x;  // 524288
    float g = bf2f(gammaH[i]);
    float hv = ldin(h0, i, bf) * g;
    int r = i >> 10, c = i & 1023;
    A3x[(size_t)r * 2560 + 512 + c] = f2bf(hv);
}

// ---- per-step kernel 1 (288 blocks, specialized) ----
// blocks 0..31:  hist GEMM + feature-reg + combine -> A3x[xi|mask], loss
// blocks 32..287: gh GEMM (K=1024) -> pbuf partials (f32)
__global__ __launch_bounds__(512) void k_step1(
    u16* __restrict__ A3x, float* __restrict__ pbuf,
    const u16* __restrict__ WhB, const u16* __restrict__ WfrB,
    const u16* __restrict__ W2B,
    const float* __restrict__ biases, const float* __restrict__ beta_all,
    const void* __restrict__ x, const void* __restrict__ mask,
    int t, const int* __restrict__ flagp,
    void* __restrict__ out, float* __restrict__ lossN, float* __restrict__ lossD) {
    __shared__ u16 smem[20736];
    __shared__ float redN[8], redD[8];
    int tid = threadIdx.x, bid = blockIdx.x;
    int lane = tid & 63, w = tid >> 6;
    int lrow = lane & 15, lseg = lane >> 4;
    int hsel = 512 + ((t & 1) << 10);

    if (bid < 32) {
        // ======== histcomb path ========
        u16* lH = smem;            // 16 x 1032
        u16* lXR = smem + 16512;   // 16 x 264
        int m0 = bid << 4;
        int c0 = w << 5;
        int bf = *flagp;
        {
            int row = tid >> 5;
            int colb = (tid & 31) << 3;
            const u16* src = A3x + (size_t)(m0 + row) * 2560 + hsel;
#pragma unroll
            for (int j = 0; j < 4; ++j) {
                int off = colb + (j << 8);
                *(uint4*)&lH[row * 1032 + off] = *(const uint4*)&src[off];
            }
        }
        __syncthreads();

        f32x4 acc[2] = {};
#pragma unroll 4
        for (int k0 = 0; k0 < 1024; k0 += 32) {
            int kk = k0 + (lseg << 3);
            s16x8 a = *(const s16x8*)&lH[lrow * 1032 + kk];
#pragma unroll
            for (int j = 0; j < 2; ++j) {
                s16x8 b = *(const s16x8*)&WhB[((size_t)(c0 + (j << 4) + lrow) << 10) + kk];
                acc[j] = __builtin_amdgcn_mfma_f32_16x16x32_bf16(a, b, acc[j], 0, 0, 0);
            }
        }

        float xhr[2][4], mvr[2][4], xvr[2][4];
#pragma unroll
        for (int j = 0; j < 2; ++j) {
            int gc = c0 + (j << 4) + lrow;
            float bhc = biases[1280 + gc];
#pragma unroll
            for (int q = 0; q < 4; ++q) {
                int r = (lseg << 2) + q;
                float v = acc[j][q] + bhc;
                int gidx = ((m0 + r) << 14) + (t << 8) + gc;
                float mv = ldin(mask, gidx, bf);
                float xv = ldin(x, gidx, bf);
                xhr[j][q] = v; mvr[j][q] = mv; xvr[j][q] = xv;
                lXR[r * 264 + gc] = f2bf(mv * xv + (1.f - mv) * v);
            }
        }
        __syncthreads();

        f32x4 accF[2] = {};
#pragma unroll
        for (int k0 = 0; k0 < 256; k0 += 32) {
            int kk = k0 + (lseg << 3);
            s16x8 a = *(const s16x8*)&lXR[lrow * 264 + kk];
#pragma unroll
            for (int j = 0; j < 2; ++j) {
                s16x8 b = *(const s16x8*)&WfrB[((size_t)(c0 + (j << 4) + lrow) << 8) + kk];
                accF[j] = __builtin_amdgcn_mfma_f32_16x16x32_bf16(a, b, accF[j], 0, 0, 0);
            }
        }

        float ln = 0.f, ldn = 0.f;
#pragma unroll
        for (int j = 0; j < 2; ++j) {
            int gc = c0 + (j << 4) + lrow;
            float bfrc = biases[1536 + gc];
#pragma unroll
            for (int q = 0; q < 4; ++q) {
                int r = (lseg << 2) + q;
                int gr = m0 + r;
                float xu = accF[j][q] + bfrc;
                float beta = beta_all[(((size_t)t * 512 + gr) << 8) + gc];
                float xc = beta * xu + (1.f - beta) * xhr[j][q];
                int gidx = (gr << 14) + (t << 8) + gc;
                float mv = mvr[j][q], xv = xvr[j][q];
                stout(out, OREC + gidx, xc, bf);
                float xi = mv * xv + (1.f - mv) * xc;
                stout(out, gidx, xi, bf);
                A3x[(size_t)gr * 2560 + gc] = f2bf(xi);
                A3x[(size_t)gr * 2560 + 256 + gc] = f2bf(mv);
                ln += fabsf(xc - xv) * mv;
                ldn += mv;
            }
        }
        for (int o = 32; o > 0; o >>= 1) { ln += __shfl_down(ln, o); ldn += __shfl_down(ldn, o); }
        if (lane == 0) { redN[w] = ln; redD[w] = ldn; }
        __syncthreads();
        if (tid == 0) {
            float sn = 0.f, sd = 0.f;
#pragma unroll
            for (int i = 0; i < 8; ++i) { sn += redN[i]; sd += redD[i]; }
            atomicAdd(&lossN[t], sn);
            atomicAdd(&lossD[t], sd);
        }
    } else {
        // ======== gh GEMM path (K=1024) ========
        u16* lds = smem;   // 2 x 8960
        int g = bid - 32;
        int m0 = (g >> 4) << 5, n0 = (g & 15) << 6;
        int wr = w & 1, wc = w >> 1;

        int br0 = tid >> 2, sg0 = tid & 3;
        int g0 = br0 >> 6;
        const u16* Bg0 = W2B + (size_t)(g0 * 1024 + n0 + (br0 & 63)) * 1536 + 512 + (sg0 << 3);
        int isB1 = (tid < 256), isA1 = (tid >= 256 && tid < 384);
        int br1 = 128 + (tid >> 2);
        const u16* Bg1 = W2B + (size_t)(2048 + n0 + (br1 & 63)) * 1536 + 512 + (sg0 << 3);
        int ar1 = (tid - 256) >> 2, sg1 = tid & 3;
        const u16* Ag1 = A3x + (size_t)(m0 + ar1) * 2560 + hsel + (sg1 << 3);

        uint4 p0, p1;
        auto issue = [&](int it) {
            int ko = it << 5;
            p0 = *(const uint4*)(Bg0 + ko);
            if (isB1) p1 = *(const uint4*)(Bg1 + ko);
            else if (isA1) p1 = *(const uint4*)(Ag1 + ko);
        };
        auto store = [&](u16* lb) {
            *(uint4*)&lb[br0 * 40 + (sg0 << 3)] = p0;
            if (isB1) *(uint4*)&lb[br1 * 40 + (sg0 << 3)] = p1;
            else if (isA1) *(uint4*)&lb[7680 + ar1 * 40 + (sg1 << 3)] = p1;
        };

        f32x4 aR = {0.f, 0.f, 0.f, 0.f}, aZ = {0.f, 0.f, 0.f, 0.f}, aN = {0.f, 0.f, 0.f, 0.f};
        issue(0);
        store(lds);
        __syncthreads();
        int cur = 0;
#pragma unroll 1
        for (int it = 0; it < 32; ++it) {
            if (it + 1 < 32) issue(it + 1);
            u16* lc = lds + (cur ? 8960 : 0);
            s16x8 a = *(const s16x8*)&lc[7680 + ((wr << 4) + lrow) * 40 + (lseg << 3)];
            int bro = ((wc << 4) + lrow) * 40 + (lseg << 3);
            s16x8 b0 = *(const s16x8*)&lc[bro];
            aR = __builtin_amdgcn_mfma_f32_16x16x32_bf16(a, b0, aR, 0, 0, 0);
            s16x8 b1 = *(const s16x8*)&lc[2560 + bro];
            aZ = __builtin_amdgcn_mfma_f32_16x16x32_bf16(a, b1, aZ, 0, 0, 0);
            s16x8 b2 = *(const s16x8*)&lc[5120 + bro];
            aN = __builtin_amdgcn_mfma_f32_16x16x32_bf16(a, b2, aN, 0, 0, 0);
            if (it + 1 < 32) store(lds + (cur ? 0 : 8960));
            __syncthreads();
            cur ^= 1;
        }

        int colR = n0 + (wc << 4) + lrow;
#pragma unroll
        for (int q = 0; q < 4; ++q) {
            int row = m0 + (wr << 4) + (lseg << 2) + q;
            float* pr = pbuf + (size_t)row * 3072 + colR;
            pr[0] = aR[q];
            pr[1024] = aZ[q];
            pr[2048] = aN[q];
        }
    }
}

// ---- per-step kernel 2 (256 blocks): gi GEMM (K=512) + GRU + decay ----
__global__ __launch_bounds__(512) void k_step2(
    u16* __restrict__ A3x, const u16* __restrict__ W2B,
    const float* __restrict__ pbuf, const float* __restrict__ biases,
    const u16* __restrict__ gammaH, int t, void* __restrict__ out,
    const int* __restrict__ flagp) {
    __shared__ u16 lds[2 * 8960];
    int tid = threadIdx.x, bid = blockIdx.x;
    int m0 = (bid >> 4) << 5, n0 = (bid & 15) << 6;
    int lane = tid & 63, w = tid >> 6;
    int wr = w & 1, wc = w >> 1;
    int lrow = lane & 15, lseg = lane >> 4;

    int br0 = tid >> 2, sg0 = tid & 3;
    int g0 = br0 >> 6;
    const u16* Bg0 = W2B + (size_t)(g0 * 1024 + n0 + (br0 & 63)) * 1536 + (sg0 << 3);
    int isB1 = (tid < 256), isA1 = (tid >= 256 && tid < 384);
    int br1 = 128 + (tid >> 2);
    const u16* Bg1 = W2B + (size_t)(2048 + n0 + (br1 & 63)) * 1536 + (sg0 << 3);
    int ar1 = (tid - 256) >> 2, sg1 = tid & 3;
    const u16* Ag1 = A3x + (size_t)(m0 + ar1) * 2560 + (sg1 << 3);

    uint4 p0, p1;
    auto issue = [&](int it) {
        int ko = it << 5;
        p0 = *(const uint4*)(Bg0 + ko);
        if (isB1) p1 = *(const uint4*)(Bg1 + ko);
        else if (isA1) p1 = *(const uint4*)(Ag1 + ko);
    };
    auto store = [&](u16* lb) {
        *(uint4*)&lb[br0 * 40 + (sg0 << 3)] = p0;
        if (isB1) *(uint4*)&lb[br1 * 40 + (sg0 << 3)] = p1;
        else if (isA1) *(uint4*)&lb[7680 + ar1 * 40 + (sg1 << 3)] = p1;
    };

    f32x4 aR = {0.f, 0.f, 0.f, 0.f}, aZ = {0.f, 0.f, 0.f, 0.f}, aN = {0.f, 0.f, 0.f, 0.f};
    issue(0);
    store(lds);
    __syncthreads();
    int cur = 0;
#pragma unroll 1
    for (int it = 0; it < 16; ++it) {
        if (it + 1 < 16) issue(it + 1);
        u16* lc = lds + (cur ? 8960 : 0);
        s16x8 a = *(const s16x8*)&lc[7680 + ((wr << 4) + lrow) * 40 + (lseg << 3)];
        int bro = ((wc << 4) + lrow) * 40 + (lseg << 3);
        s16x8 b0 = *(const s16x8*)&lc[bro];
        aR = __builtin_amdgcn_mfma_f32_16x16x32_bf16(a, b0, aR, 0, 0, 0);
        s16x8 b1 = *(const s16x8*)&lc[2560 + bro];
        aZ = __builtin_amdgcn_mfma_f32_16x16x32_bf16(a, b1, aZ, 0, 0, 0);
        s16x8 b2 = *(const s16x8*)&lc[5120 + bro];
        aN = __builtin_amdgcn_mfma_f32_16x16x32_bf16(a, b2, aN, 0, 0, 0);
        if (it + 1 < 16) store(lds + (cur ? 0 : 8960));
        __syncthreads();
        cur ^= 1;
    }

    int bf = *flagp;
    int hsel = 512 + ((t & 1) << 10);
    int nseg = 512 + (((t + 1) & 1) << 10);
    int last = (t == 63);
    int colR = n0 + (wc << 4) + lrow;
    float bRi = biases[2048 + colR] + biases[5120 + colR];
    float bZi = biases[3072 + colR] + biases[6144 + colR];
    float bNi = biases[4096 + colR];
    float bNh = biases[7168 + colR];
#pragma unroll
    for (int q = 0; q < 4; ++q) {
        int row = m0 + (wr << 4) + (lseg << 2) + q;
        const float* pr = pbuf + (size_t)row * 3072 + colR;
        float rr = 1.f / (1.f + expf(-(aR[q] + pr[0] + bRi)));
        float zz = 1.f / (1.f + expf(-(aZ[q] + pr[1024] + bZi)));
        float nn = tanhf(aN[q] + bNi + rr * (pr[2048] + bNh));
        float hp = bf2f(A3x[(size_t)row * 2560 + hsel + colR]);
        float hv = (1.f - zz) * nn + zz * hp;
        if (!last) {
            hv *= bf2f(gammaH[(((size_t)(t + 1) * 512 + row) << 10) + colR]);
            A3x[(size_t)row * 2560 + nseg + colR] = f2bf(hv);
        } else {
            stout(out, OH + (row << 10) + colR, hv, bf);
        }
    }
}

// ---- epilogue ----
__global__ void k_loss(const float* __restrict__ lossN, const float* __restrict__ lossD,
                       void* __restrict__ out, const int* __restrict__ flagp) {
    int t = threadIdx.x;  // 64
    float v = lossN[t] / (lossD[t] + 1e-12f);
    for (int o = 32; o > 0; o >>= 1) v += __shfl_down(v, o);
    if (t == 0) {
        int bf = *flagp;
        stout(out, OLOSS, v, bf);
        stout(out, OLOSS + 1, 0.f, bf);
    }
}

extern "C" void kernel_launch(void* const* d_in, const int* in_sizes, int n_in,
                              void* d_out, int out_size, void* d_ws, size_t ws_size,
                              hipStream_t stream) {
    (void)in_sizes; (void)n_in; (void)out_size; (void)ws_size;
    const void* x = d_in[0];
    const void* mask = d_in[1];
    const void* deltas = d_in[2];
    const void* h0 = d_in[3];
    const void* Wdh = d_in[4];  const void* bdh = d_in[5];
    const void* Wdx = d_in[6];  const void* bdx = d_in[7];
    const void* Wh = d_in[8];   const void* bh = d_in[9];
    const void* Wfr = d_in[10]; const void* bfr = d_in[11];
    const void* Wwc = d_in[12]; const void* bwc = d_in[13];
    const void* Wih = d_in[14]; const void* bih = d_in[15];
    const void* Whh = d_in[16]; const void* bhh = d_in[17];

    char* cur = (char*)d_ws;
    auto carve = [&](size_t bytes) -> char* {
        char* p = cur; cur += (bytes + 255) & ~(size_t)255; return p;
    };
    int* flag = (int*)carve(sizeof(int));
    float* lossN = (float*)carve(64 * 4);
    float* lossD = (float*)carve(64 * 4);
    float* wdxd = (float*)carve(256 * 4);
    float* biasesF = (float*)carve(8192 * 4);
    u16* WdhB = (u16*)carve(262144 * 2);
    u16* WhB = (u16*)carve(262144 * 2);
    u16* WfrB = (u16*)carve(65536 * 2);
    u16* WwcB = (u16*)carve(131072 * 2);
    u16* W2B = (u16*)carve((size_t)4718592 * 2);
    u16* A3x = (u16*)carve((size_t)512 * 2560 * 2);
    float* pbuf = (float*)carve((size_t)512 * 3072 * 4);
    u16* dbf_all = (u16*)carve((size_t)8388608 * 2);
    u16* A2_all = (u16*)carve((size_t)16777216 * 2);
    u16* gammaH_all = (u16*)carve((size_t)33554432 * 2);
    float* beta_all = (float*)carve((size_t)8388608 * 4);

    float* bdhF = biasesF;
    float* bdxF = biasesF + 1024;

    // prologue: dtype detect + weight prep
    k_zero<<<1, 64, 0, stream>>>(flag, lossN, lossD);
    k_detect<<<256, 256, 0, stream>>>((const u32*)mask, flag);
    k_cvt_bf<<<1024, 256, 0, stream>>>(Wdh, WdhB, 262144, flag);
    k_cvt_bf<<<1024, 256, 0, stream>>>(Wh, WhB, 262144, flag);
    k_cvt_bf<<<256, 256, 0, stream>>>(Wfr, WfrB, 65536, flag);
    k_cvt_bf<<<512, 256, 0, stream>>>(Wwc, WwcB, 131072, flag);
    k_packW2<<<3072, 256, 0, stream>>>(Wih, Whh, W2B, flag);
    k_cvt_biases<<<32, 256, 0, stream>>>(bdh, bdx, bh, bfr, bwc, bih, bhh, biasesF, flag);
    k_fixup<<<1, 256, 0, stream>>>(WfrB, wdxd, Wdx, flag);

    // precompute: gamma_x/mask pack, gamma_h for all t, beta for all t, h init
    k_pack<<<8192, 256, 0, stream>>>(deltas, mask, flag, wdxd, bdxF, dbf_all, A2_all);
    k_gammaH<<<dim3(512, 16), 256, 0, stream>>>(dbf_all, WdhB, bdhF, gammaH_all);
    k_beta<<<dim3(512, 4), 256, 0, stream>>>(A2_all, WwcB, biasesF + 1792, beta_all);
    k_hinit<<<2048, 256, 0, stream>>>(h0, flag, gammaH_all, A3x);

    for (int t = 0; t < 64; ++t) {
        k_step1<<<288, 512, 0, stream>>>(A3x, pbuf, WhB, WfrB, W2B, biasesF, beta_all,
                                         x, mask, t, flag, d_out, lossN, lossD);
        k_step2<<<256, 512, 0, stream>>>(A3x, W2B, pbuf, biasesF, gammaH_all, t, d_out, flag);
    }
    k_loss<<<1, 64, 0, stream>>>(lossN, lossD, d_out, flag);
}